// Round 1
// baseline (1634.464 us; speedup 1.0000x reference)
//
#include <hip/hip_runtime.h>
#include <math.h>

#define EPSV 1e-5f

// ---------------- prep: transposes + attn2-collapse vectors ----------------
__global__ __launch_bounds__(256) void prep_kernel(
    const float* __restrict__ w3, const float* __restrict__ w4,
    const float* __restrict__ mw1, const float* __restrict__ mw2,
    const float* __restrict__ sw2, const float* __restrict__ b4,
    const float* __restrict__ sb2,
    float* __restrict__ w3T, float* __restrict__ w4T,
    float* __restrict__ mw1T, float* __restrict__ mw2T,
    float* __restrict__ u, float* __restrict__ ub)
{
    int tid = blockIdx.x * blockDim.x + threadIdx.x;
    int nthr = gridDim.x * blockDim.x;
    for (int i = tid; i < 512 * 512; i += nthr) {
        int o = i >> 9, c = i & 511;
        w3T[c * 512 + o]  = w3[o * 512 + c];
        w4T[c * 512 + o]  = w4[o * 512 + c];
        mw2T[c * 512 + o] = mw2[o * 512 + c];
    }
    for (int i = tid; i < 256 * 256; i += nthr) {
        int o = i >> 8, c = i & 255;
        mw1T[c * 256 + o] = mw1[o * 256 + c];
    }
    if (tid < 512) {
        float acc = 0.f;
        for (int o = 0; o < 512; ++o) acc += sw2[o] * w4[o * 512 + tid];
        u[tid] = acc;
    }
    if (tid == 0) {
        float acc = sb2[0];
        for (int o = 0; o < 512; ++o) acc += sw2[o] * b4[o];
        ub[0] = acc;
    }
}

// ---------------- KNN: one block per group ----------------
__global__ __launch_bounds__(256) void knn_kernel(
    const float* __restrict__ xyz, const int* __restrict__ cidx,
    int* __restrict__ knn_idx, float* __restrict__ out_center)
{
    __shared__ float d2s[8192];
    __shared__ float wv[4];
    __shared__ int   wi[4];
    int g = blockIdx.x;          // 0..4095
    int b = g >> 9;
    int t = threadIdx.x;
    const float* xb = xyz + (size_t)b * 8192 * 3;
    int ci = cidx[g];
    float cx = xb[ci * 3 + 0], cy = xb[ci * 3 + 1], cz = xb[ci * 3 + 2];
    float c2 = cx * cx + cy * cy + cz * cz;
    if (t < 3) out_center[g * 3 + t] = xb[ci * 3 + t];
    for (int i = 0; i < 32; ++i) {
        int n = t + (i << 8);
        float x = xb[n * 3 + 0], y = xb[n * 3 + 1], z = xb[n * 3 + 2];
        float n2 = x * x + y * y + z * z;
        d2s[n] = c2 + n2 - 2.f * (cx * x + cy * y + cz * z);
    }
    __syncthreads();
    int lane = t & 63, w = t >> 6;
    for (int k = 0; k < 32; ++k) {
        float best = INFINITY;
        int bi = 0x7fffffff;
        for (int i = 0; i < 32; ++i) {
            int n = t + (i << 8);
            float v = d2s[n];
            if (v < best) { best = v; bi = n; }   // first (lowest n) wins ties
        }
        for (int off = 32; off > 0; off >>= 1) {
            float ov = __shfl_down(best, off);
            int   oi = __shfl_down(bi, off);
            if (ov < best || (ov == best && oi < bi)) { best = ov; bi = oi; }
        }
        if (lane == 0) { wv[w] = best; wi[w] = bi; }
        __syncthreads();
        if (t == 0) {
            float bv = wv[0]; int bb = wi[0];
            for (int j = 1; j < 4; ++j)
                if (wv[j] < bv || (wv[j] == bv && wi[j] < bb)) { bv = wv[j]; bb = wi[j]; }
            knn_idx[g * 32 + k] = bb;
            d2s[bb] = INFINITY;
        }
        __syncthreads();
    }
}

// ---------------- fused per-group MLP ----------------
__global__ __launch_bounds__(256) void mlp_kernel(
    const float* __restrict__ xyz, const int* __restrict__ cidx,
    const int* __restrict__ knn_idx,
    const float* __restrict__ w1, const float* __restrict__ b1,
    const float* __restrict__ g1, const float* __restrict__ be1,
    const float* __restrict__ m1, const float* __restrict__ v1,
    const float* __restrict__ w2, const float* __restrict__ b2,
    const float* __restrict__ sw1, const float* __restrict__ sb1,
    const float* __restrict__ mw1T, const float* __restrict__ mb1,
    const float* __restrict__ w3T, const float* __restrict__ b3,
    const float* __restrict__ g2, const float* __restrict__ be2,
    const float* __restrict__ m2, const float* __restrict__ v2,
    const float* __restrict__ u, const float* __restrict__ ubp,
    const float* __restrict__ w4T, const float* __restrict__ b4,
    const float* __restrict__ mw2T, const float* __restrict__ mb2,
    float* __restrict__ out_fg2)
{
    __shared__ float feat[32][12];
    __shared__ float x1s[32][132];
    __shared__ float x2s[32][260];
    __shared__ float sc[32];
    __shared__ float sm[32];
    __shared__ float pool1[256];
    __shared__ float fgs[256];
    __shared__ float yvv[512];
    __shared__ float pool2[512];
    __shared__ float wred[4][32];

    int g = blockIdx.x;
    int b = g >> 9;
    int t = threadIdx.x;
    const float* xb = xyz + (size_t)b * 8192 * 3;
    int ci = cidx[g];
    float cx = xb[ci * 3 + 0], cy = xb[ci * 3 + 1], cz = xb[ci * 3 + 2];

    // ---- feat [32][10] ----
    if (t < 32) {
        int n = knn_idx[g * 32 + t];
        float nx = xb[n * 3 + 0], ny = xb[n * 3 + 1], nz = xb[n * 3 + 2];
        float rx = cx - nx, ry = cy - ny, rz = cz - nz;
        float rd = sqrtf(rx * rx + ry * ry + rz * rz);
        feat[t][0] = rd; feat[t][1] = rx; feat[t][2] = ry; feat[t][3] = rz;
        feat[t][4] = cx; feat[t][5] = cy; feat[t][6] = cz;
        feat[t][7] = nx; feat[t][8] = ny; feat[t][9] = nz;
    }
    __syncthreads();

    // ---- conv1 + BN + ReLU -> x1s [32][128] ----
    for (int i = 0; i < 16; ++i) {
        int flat = t + (i << 8);
        int k = flat >> 7, o = flat & 127;
        const float* wr = w1 + o * 10;
        float acc = b1[o];
        #pragma unroll
        for (int c = 0; c < 10; ++c) acc += feat[k][c] * wr[c];
        float s = g1[o] * rsqrtf(v1[o] + EPSV);
        acc = (acc - m1[o]) * s + be1[o];
        x1s[k][o] = fmaxf(acc, 0.f);
    }
    __syncthreads();

    // ---- conv2 -> x2s [32][256] (thread t = out channel) ----
    {
        int o = t;
        float acc[32];
        #pragma unroll
        for (int k = 0; k < 32; ++k) acc[k] = b2[o];
        const float* wr = w2 + o * 128;
        for (int c = 0; c < 128; c += 4) {
            float4 wvv = *(const float4*)(wr + c);
            #pragma unroll
            for (int k = 0; k < 32; ++k) {
                float4 xv = *(const float4*)(&x1s[k][c]);
                acc[k] += xv.x * wvv.x + xv.y * wvv.y + xv.z * wvv.z + xv.w * wvv.w;
            }
        }
        #pragma unroll
        for (int k = 0; k < 32; ++k) x2s[k][o] = acc[k];
    }
    __syncthreads();

    // ---- attn1 scores ----
    if (t < 32) {
        float acc = sb1[0];
        for (int o = 0; o < 256; o += 4) {
            float4 sv = *(const float4*)(sw1 + o);
            float4 xv = *(const float4*)(&x2s[t][o]);
            acc += xv.x * sv.x + xv.y * sv.y + xv.z * sv.z + xv.w * sv.w;
        }
        sc[t] = acc;
    }
    __syncthreads();
    if (t < 32) {
        float mx = -INFINITY;
        for (int k = 0; k < 32; ++k) mx = fmaxf(mx, sc[k]);
        float ssum = 0.f;
        for (int k = 0; k < 32; ++k) ssum += expf(sc[k] - mx);
        sm[t] = expf(sc[t] - mx) / ssum;
    }
    __syncthreads();
    // pooled1
    {
        float acc = 0.f;
        for (int k = 0; k < 32; ++k) acc += sm[k] * x2s[k][t];
        pool1[t] = acc;
    }
    __syncthreads();
    // fg = pooled1 @ mw1^T + mb1
    {
        float acc = mb1[t];
        for (int c = 0; c < 256; ++c) acc += pool1[c] * mw1T[c * 256 + t];
        fgs[t] = acc;
    }
    __syncthreads();

    // ---- conv3: x4 = relu(bn2([fg|x2] @ w3^T + b3)), x4 kept in registers ----
    int o0 = t, o1 = t + 256;
    float f0 = b3[o0], f1 = b3[o1];
    for (int c = 0; c < 256; ++c) {
        float fv = fgs[c];
        f0 += fv * w3T[c * 512 + o0];
        f1 += fv * w3T[c * 512 + o1];
    }
    float a0[32], a1[32];
    #pragma unroll
    for (int k = 0; k < 32; ++k) { a0[k] = f0; a1[k] = f1; }
    const float* w3b = w3T + 256 * 512;
    for (int c = 0; c < 256; c += 4) {
        float wa0 = w3b[(c + 0) * 512 + o0], wb0 = w3b[(c + 0) * 512 + o1];
        float wa1 = w3b[(c + 1) * 512 + o0], wb1 = w3b[(c + 1) * 512 + o1];
        float wa2 = w3b[(c + 2) * 512 + o0], wb2 = w3b[(c + 2) * 512 + o1];
        float wa3 = w3b[(c + 3) * 512 + o0], wb3 = w3b[(c + 3) * 512 + o1];
        #pragma unroll
        for (int k = 0; k < 32; ++k) {
            float4 xv = *(const float4*)(&x2s[k][c]);
            a0[k] += xv.x * wa0 + xv.y * wa1 + xv.z * wa2 + xv.w * wa3;
            a1[k] += xv.x * wb0 + xv.y * wb1 + xv.z * wb2 + xv.w * wb3;
        }
    }
    {
        float s0 = g2[o0] * rsqrtf(v2[o0] + EPSV), sh0 = be2[o0], mm0 = m2[o0];
        float s1 = g2[o1] * rsqrtf(v2[o1] + EPSV), sh1 = be2[o1], mm1 = m2[o1];
        #pragma unroll
        for (int k = 0; k < 32; ++k) {
            a0[k] = fmaxf((a0[k] - mm0) * s0 + sh0, 0.f);
            a1[k] = fmaxf((a1[k] - mm1) * s1 + sh1, 0.f);
        }
    }

    // ---- attn2 scores via u-collapse: sc2[k] = x4[k,:].u + ub ----
    {
        float u0 = u[o0], u1 = u[o1];
        int lane = t & 63, w = t >> 6;
        #pragma unroll
        for (int k = 0; k < 32; ++k) {
            float p = u0 * a0[k] + u1 * a1[k];
            p += __shfl_down(p, 32);
            p += __shfl_down(p, 16);
            p += __shfl_down(p, 8);
            p += __shfl_down(p, 4);
            p += __shfl_down(p, 2);
            p += __shfl_down(p, 1);
            if (lane == 0) wred[w][k] = p;
        }
    }
    __syncthreads();
    if (t < 32) {
        sc[t] = wred[0][t] + wred[1][t] + wred[2][t] + wred[3][t] + ubp[0];
    }
    __syncthreads();
    if (t < 32) {
        float mx = -INFINITY;
        for (int k = 0; k < 32; ++k) mx = fmaxf(mx, sc[k]);
        float ssum = 0.f;
        for (int k = 0; k < 32; ++k) ssum += expf(sc[k] - mx);
        sm[t] = expf(sc[t] - mx) / ssum;
    }
    __syncthreads();

    // ---- y = sum_k s[k]*x4[k,:] (in registers) ----
    {
        float y0 = 0.f, y1 = 0.f;
        #pragma unroll
        for (int k = 0; k < 32; ++k) { float s = sm[k]; y0 += s * a0[k]; y1 += s * a1[k]; }
        yvv[o0] = y0; yvv[o1] = y1;
    }
    __syncthreads();

    // ---- pooled2 = y @ w4^T + b4 ----
    {
        float p0 = b4[o0], p1 = b4[o1];
        for (int c = 0; c < 512; ++c) {
            float yc = yvv[c];
            p0 += yc * w4T[c * 512 + o0];
            p1 += yc * w4T[c * 512 + o1];
        }
        pool2[o0] = p0; pool2[o1] = p1;
    }
    __syncthreads();

    // ---- fg2 = pooled2 @ mw2^T + mb2 -> out ----
    {
        float q0 = mb2[o0], q1 = mb2[o1];
        for (int c = 0; c < 512; ++c) {
            float pc = pool2[c];
            q0 += pc * mw2T[c * 512 + o0];
            q1 += pc * mw2T[c * 512 + o1];
        }
        out_fg2[(size_t)g * 512 + o0] = q0;
        out_fg2[(size_t)g * 512 + o1] = q1;
    }
}

extern "C" void kernel_launch(void* const* d_in, const int* in_sizes, int n_in,
                              void* d_out, int out_size, void* d_ws, size_t ws_size,
                              hipStream_t stream) {
    const float* xyz  = (const float*)d_in[0];
    const int*   cidx = (const int*)d_in[1];
    const float* w1   = (const float*)d_in[2];
    const float* b1   = (const float*)d_in[3];
    const float* g1   = (const float*)d_in[4];
    const float* be1  = (const float*)d_in[5];
    const float* m1   = (const float*)d_in[6];
    const float* v1   = (const float*)d_in[7];
    const float* w2   = (const float*)d_in[8];
    const float* b2   = (const float*)d_in[9];
    const float* sw1  = (const float*)d_in[10];
    const float* sb1  = (const float*)d_in[11];
    const float* mw1  = (const float*)d_in[12];
    const float* mb1  = (const float*)d_in[13];
    const float* w3   = (const float*)d_in[14];
    const float* b3   = (const float*)d_in[15];
    const float* g2   = (const float*)d_in[16];
    const float* be2  = (const float*)d_in[17];
    const float* m2   = (const float*)d_in[18];
    const float* v2   = (const float*)d_in[19];
    const float* w4   = (const float*)d_in[20];
    const float* b4   = (const float*)d_in[21];
    const float* sw2  = (const float*)d_in[22];
    const float* sb2  = (const float*)d_in[23];
    const float* mw2  = (const float*)d_in[24];
    const float* mb2  = (const float*)d_in[25];

    float* out = (float*)d_out;
    char* ws = (char*)d_ws;
    int*   knn_idx = (int*)ws;                       // 4096*32 ints = 512KB
    float* w3T  = (float*)(ws + 524288);             // 1MB
    float* w4T  = (float*)(ws + 1572864);            // 1MB
    float* mw2T = (float*)(ws + 2621440);            // 1MB
    float* mw1T = (float*)(ws + 3670016);            // 256KB
    float* u    = (float*)(ws + 3932160);            // 2KB
    float* ub   = (float*)(ws + 3934208);            // 4B

    prep_kernel<<<512, 256, 0, stream>>>(w3, w4, mw1, mw2, sw2, b4, sb2,
                                         w3T, w4T, mw1T, mw2T, u, ub);
    knn_kernel<<<4096, 256, 0, stream>>>(xyz, cidx, knn_idx, out);
    mlp_kernel<<<4096, 256, 0, stream>>>(xyz, cidx, knn_idx,
                                         w1, b1, g1, be1, m1, v1,
                                         w2, b2, sw1, sb1, mw1T, mb1,
                                         w3T, b3, g2, be2, m2, v2,
                                         u, ub, w4T, b4, mw2T, mb2,
                                         out + 12288);
}

// Round 2
// 834.220 us; speedup vs baseline: 1.9593x; 1.9593x over previous
//
#include <hip/hip_runtime.h>
#include <math.h>

#define EPSV 1e-5f

typedef __attribute__((ext_vector_type(8))) short bf16x8;
typedef __attribute__((ext_vector_type(4))) float f32x4;

#define MFMA16(a, b, c) __builtin_amdgcn_mfma_f32_16x16x32_bf16(a, b, c, 0, 0, 0)

__device__ __forceinline__ short f2bf(float x) {
    unsigned u = __float_as_uint(x);
    unsigned r = (u + 0x7fffu + ((u >> 16) & 1u)) >> 16;
    return (short)r;
}
__device__ __forceinline__ float bf2f(short h) {
    return __uint_as_float(((unsigned)(unsigned short)h) << 16);
}
__device__ __forceinline__ void bsplit(float x, short& h, short& l) {
    h = f2bf(x);
    l = f2bf(x - bf2f(h));
}

// ---------------- prep_misc: scales, transposes, fragment packing, u/ub/bb ---
__global__ __launch_bounds__(256) void prep_misc(
    const float* __restrict__ w1, const float* __restrict__ g1,
    const float* __restrict__ be1, const float* __restrict__ m1,
    const float* __restrict__ v1,
    const float* __restrict__ w2,
    const float* __restrict__ mw1,
    const float* __restrict__ w3,
    const float* __restrict__ g2, const float* __restrict__ be2,
    const float* __restrict__ m2, const float* __restrict__ v2,
    const float* __restrict__ w4, const float* __restrict__ sw2,
    const float* __restrict__ b4, const float* __restrict__ sb2,
    const float* __restrict__ mw2, const float* __restrict__ mb2,
    float* __restrict__ w3fgT, float* __restrict__ mw1T,
    short* __restrict__ w2fh, short* __restrict__ w2fl,
    short* __restrict__ w3fh, short* __restrict__ w3fl,
    float* __restrict__ sc1, float* __restrict__ sh1,
    float* __restrict__ sc2, float* __restrict__ sh2,
    float* __restrict__ u, float* __restrict__ bb, float* __restrict__ ub)
{
    int tid = blockIdx.x * blockDim.x + threadIdx.x;
    int nthr = gridDim.x * blockDim.x;
    // w3fgT[c*512+o] = w3[o][c], c<256
    for (int i = tid; i < 512 * 256; i += nthr) {
        int o = i & 511, c = i >> 9;
        w3fgT[c * 512 + o] = w3[o * 512 + c];
    }
    // mw1T
    for (int i = tid; i < 256 * 256; i += nthr) {
        int o = i & 255, c = i >> 8;
        mw1T[c * 256 + o] = mw1[o * 256 + c];
    }
    // w2 fragments: value = w2[o=ct*16+(lane&15)][k=ks*32+(lane>>4)*8+j]
    for (int i = tid; i < 32768; i += nthr) {
        int j = i & 7, lane = (i >> 3) & 63, rest = i >> 9;
        int ks = rest & 3, ct = rest >> 2;
        int o = ct * 16 + (lane & 15);
        int k = ks * 32 + (lane >> 4) * 8 + j;
        short h, l; bsplit(w2[o * 128 + k], h, l);
        w2fh[i] = h; w2fl[i] = l;
    }
    // w3 fragments (c in [256,512)): value = w3[o=ct*16+(lane&15)][256+ks*32+(lane>>4)*8+j]
    for (int i = tid; i < 131072; i += nthr) {
        int j = i & 7, lane = (i >> 3) & 63, rest = i >> 9;
        int ks = rest & 7, ct = rest >> 3;
        int o = ct * 16 + (lane & 15);
        int c = 256 + ks * 32 + (lane >> 4) * 8 + j;
        short h, l; bsplit(w3[o * 512 + c], h, l);
        w3fh[i] = h; w3fl[i] = l;
    }
    // BN folds
    for (int i = tid; i < 128; i += nthr) {
        float s = g1[i] * rsqrtf(v1[i] + EPSV);
        sc1[i] = s; sh1[i] = be1[i] - m1[i] * s;
    }
    for (int i = tid; i < 512; i += nthr) {
        float s = g2[i] * rsqrtf(v2[i] + EPSV);
        sc2[i] = s; sh2[i] = be2[i] - m2[i] * s;
    }
    // u[c] = sum_o sw2[o]*w4[o][c]
    for (int c = tid; c < 512; c += nthr) {
        float acc = 0.f;
        for (int o = 0; o < 512; ++o) acc += sw2[o] * w4[o * 512 + c];
        u[c] = acc;
    }
    // bb[q] = mb2[q] + sum_o mw2[q][o]*b4[o]
    for (int qq = tid; qq < 512; qq += nthr) {
        float acc = mb2[qq];
        for (int o = 0; o < 512; ++o) acc += mw2[qq * 512 + o] * b4[o];
        bb[qq] = acc;
    }
    if (tid == 0) {
        float acc = sb2[0];
        for (int o = 0; o < 512; ++o) acc += sw2[o] * b4[o];
        ub[0] = acc;
    }
}

// ---------------- prep_mgemm: MT[c][q] = sum_o mw2[q][o]*w4[o][c] ------------
__global__ __launch_bounds__(256) void prep_mgemm(
    const float* __restrict__ mw2, const float* __restrict__ w4,
    float* __restrict__ MT)
{
    __shared__ float row[512];
    int qq = blockIdx.x, t = threadIdx.x;
    row[t] = mw2[qq * 512 + t];
    row[t + 256] = mw2[qq * 512 + t + 256];
    __syncthreads();
    float a0 = 0.f, a1 = 0.f;
    for (int o = 0; o < 512; ++o) {
        float m = row[o];
        a0 += m * w4[o * 512 + t];
        a1 += m * w4[o * 512 + t + 256];
    }
    MT[t * 512 + qq] = a0;
    MT[(t + 256) * 512 + qq] = a1;
}

// ---------------- KNN: one block per group (unchanged, passed R1) ------------
__global__ __launch_bounds__(256) void knn_kernel(
    const float* __restrict__ xyz, const int* __restrict__ cidx,
    int* __restrict__ knn_idx, float* __restrict__ out_center)
{
    __shared__ float d2s[8192];
    __shared__ float wvv[4];
    __shared__ int   wii[4];
    int g = blockIdx.x;
    int b = g >> 9;
    int t = threadIdx.x;
    const float* xb = xyz + (size_t)b * 8192 * 3;
    int ci = cidx[g];
    float cx = xb[ci * 3 + 0], cy = xb[ci * 3 + 1], cz = xb[ci * 3 + 2];
    float c2 = cx * cx + cy * cy + cz * cz;
    if (t < 3) out_center[g * 3 + t] = xb[ci * 3 + t];
    for (int i = 0; i < 32; ++i) {
        int n = t + (i << 8);
        float x = xb[n * 3 + 0], y = xb[n * 3 + 1], z = xb[n * 3 + 2];
        float n2 = x * x + y * y + z * z;
        d2s[n] = c2 + n2 - 2.f * (cx * x + cy * y + cz * z);
    }
    __syncthreads();
    int lane = t & 63, w = t >> 6;
    for (int k = 0; k < 32; ++k) {
        float best = INFINITY;
        int bi = 0x7fffffff;
        for (int i = 0; i < 32; ++i) {
            int n = t + (i << 8);
            float v = d2s[n];
            if (v < best) { best = v; bi = n; }
        }
        for (int off = 32; off > 0; off >>= 1) {
            float ov = __shfl_down(best, off);
            int   oi = __shfl_down(bi, off);
            if (ov < best || (ov == best && oi < bi)) { best = ov; bi = oi; }
        }
        if (lane == 0) { wvv[w] = best; wii[w] = bi; }
        __syncthreads();
        if (t == 0) {
            float bv = wvv[0]; int bbx = wii[0];
            for (int j = 1; j < 4; ++j)
                if (wvv[j] < bv || (wvv[j] == bv && wii[j] < bbx)) { bv = wvv[j]; bbx = wii[j]; }
            knn_idx[g * 32 + k] = bbx;
            d2s[bbx] = INFINITY;
        }
        __syncthreads();
    }
}

// ---------------- fused per-group MLP with MFMA conv2/conv3 ------------------
__global__ __launch_bounds__(256) void mlp_kernel(
    const float* __restrict__ xyz, const int* __restrict__ cidx,
    const int* __restrict__ knn_idx,
    const float* __restrict__ w1, const float* __restrict__ b1,
    const float* __restrict__ sc1, const float* __restrict__ sh1,
    const short* __restrict__ w2fh, const short* __restrict__ w2fl,
    const float* __restrict__ b2,
    const float* __restrict__ sw1, const float* __restrict__ sb1,
    const float* __restrict__ mw1T, const float* __restrict__ mb1,
    const float* __restrict__ w3fgT, const float* __restrict__ b3,
    const float* __restrict__ sc2, const float* __restrict__ sh2,
    const short* __restrict__ w3fh, const short* __restrict__ w3fl,
    const float* __restrict__ u, const float* __restrict__ ubp,
    const float* __restrict__ MT, const float* __restrict__ bb,
    float* __restrict__ out_fg2)
{
    __shared__ __align__(16) char smem[39680];
    short* x2h = (short*)smem;                 // [32*256] bf16, XOR-swizzled
    short* x2l = (short*)(smem + 16384);
    short* x1h = (short*)smem;                 // overlay: [32*128]
    short* x1l = (short*)(smem + 8192);
    float* feat = (float*)(smem + 16384);      // overlay in x2l: [32][12]
    float* wred = (float*)(smem + 32768);      // [4][32]
    float* scs  = (float*)(smem + 33280);      // [32]
    float* sms  = (float*)(smem + 33408);      // [32]
    float* pool1 = (float*)(smem + 33536);     // [256]
    float* fgs   = (float*)(smem + 34560);     // [256]
    float* fgpart = (float*)(smem + 35584);    // [512]
    float* yvv    = (float*)(smem + 37632);    // [512]

    int g = blockIdx.x, b = g >> 9, t = threadIdx.x;
    int lane = t & 63, wv = t >> 6, q = lane >> 4, r = lane & 15;
    const float* xb = xyz + (size_t)b * 8192 * 3;
    int ci = cidx[g];
    float cx = xb[ci * 3 + 0], cy = xb[ci * 3 + 1], cz = xb[ci * 3 + 2];

    // ---- feat [32][10] ----
    if (t < 32) {
        int n = knn_idx[g * 32 + t];
        float nx = xb[n * 3 + 0], ny = xb[n * 3 + 1], nz = xb[n * 3 + 2];
        float rx = cx - nx, ry = cy - ny, rz = cz - nz;
        float rd = sqrtf(rx * rx + ry * ry + rz * rz);
        float* fr = feat + t * 12;
        fr[0] = rd; fr[1] = rx; fr[2] = ry; fr[3] = rz;
        fr[4] = cx; fr[5] = cy; fr[6] = cz;
        fr[7] = nx; fr[8] = ny; fr[9] = nz;
    }
    __syncthreads();

    // ---- conv1 + BN + ReLU -> x1 hi/lo (swizzled) ----
    for (int i = 0; i < 16; ++i) {
        int flat = t + (i << 8);
        int k = flat >> 7, o = flat & 127;
        const float* wr = w1 + o * 10;
        const float* fr = feat + k * 12;
        float acc = b1[o];
        #pragma unroll
        for (int c = 0; c < 10; ++c) acc += fr[c] * wr[c];
        acc = fmaxf(acc * sc1[o] + sh1[o], 0.f);
        short h, l; bsplit(acc, h, l);
        int idx = k * 128 + (o ^ ((k & 7) << 3));
        x1h[idx] = h; x1l[idx] = l;
    }
    __syncthreads();

    // ---- conv2 via MFMA (M=32, N=256, K=128), bf16x3 ----
    f32x4 acc2[2][4];
    #pragma unroll
    for (int rt = 0; rt < 2; ++rt)
        #pragma unroll
        for (int ctl = 0; ctl < 4; ++ctl) {
            float bv = b2[(wv * 4 + ctl) * 16 + r];
            acc2[rt][ctl] = (f32x4){bv, bv, bv, bv};
        }
    for (int ks = 0; ks < 4; ++ks) {
        bf16x8 ah[2], al[2];
        #pragma unroll
        for (int rt = 0; rt < 2; ++rt) {
            int row = rt * 16 + r;
            int kk = ks * 32 + q * 8;
            int idx = row * 128 + (kk ^ ((row & 7) << 3));
            ah[rt] = *(const bf16x8*)(x1h + idx);
            al[rt] = *(const bf16x8*)(x1l + idx);
        }
        #pragma unroll
        for (int ctl = 0; ctl < 4; ++ctl) {
            int ct = wv * 4 + ctl;
            size_t woff = ((size_t)(ct * 4 + ks) * 64 + lane) * 8;
            bf16x8 bh = *(const bf16x8*)(w2fh + woff);
            bf16x8 bl = *(const bf16x8*)(w2fl + woff);
            #pragma unroll
            for (int rt = 0; rt < 2; ++rt) {
                acc2[rt][ctl] = MFMA16(al[rt], bh, acc2[rt][ctl]);
                acc2[rt][ctl] = MFMA16(ah[rt], bl, acc2[rt][ctl]);
                acc2[rt][ctl] = MFMA16(ah[rt], bh, acc2[rt][ctl]);
            }
        }
    }

    // ---- attn1 scores from C-frags ----
    {
        float sw1v[4];
        #pragma unroll
        for (int ctl = 0; ctl < 4; ++ctl) sw1v[ctl] = sw1[(wv * 4 + ctl) * 16 + r];
        float sco[2][4];
        #pragma unroll
        for (int rt = 0; rt < 2; ++rt)
            #pragma unroll
            for (int j = 0; j < 4; ++j) {
                float s = 0.f;
                #pragma unroll
                for (int ctl = 0; ctl < 4; ++ctl) s += sw1v[ctl] * acc2[rt][ctl][j];
                sco[rt][j] = s;
            }
        #pragma unroll
        for (int off = 1; off < 16; off <<= 1)
            #pragma unroll
            for (int rt = 0; rt < 2; ++rt)
                #pragma unroll
                for (int j = 0; j < 4; ++j) sco[rt][j] += __shfl_xor(sco[rt][j], off);
        if (r == 0) {
            #pragma unroll
            for (int rt = 0; rt < 2; ++rt)
                #pragma unroll
                for (int j = 0; j < 4; ++j)
                    wred[wv * 32 + rt * 16 + q * 4 + j] = sco[rt][j];
        }
    }
    __syncthreads();
    if (t < 32) scs[t] = wred[t] + wred[32 + t] + wred[64 + t] + wred[96 + t] + sb1[0];
    __syncthreads();
    if (t < 32) {
        float mx = -INFINITY;
        for (int k = 0; k < 32; ++k) mx = fmaxf(mx, scs[k]);
        float ssum = 0.f;
        for (int k = 0; k < 32; ++k) ssum += expf(scs[k] - mx);
        sms[t] = expf(scs[t] - mx) / ssum;
    }
    __syncthreads();

    // ---- pool1 from C-frags; write x2 hi/lo (x1 region is dead now) ----
    {
        float smv[2][4];
        #pragma unroll
        for (int rt = 0; rt < 2; ++rt)
            #pragma unroll
            for (int j = 0; j < 4; ++j) smv[rt][j] = sms[rt * 16 + q * 4 + j];
        #pragma unroll
        for (int ctl = 0; ctl < 4; ++ctl) {
            float p = 0.f;
            #pragma unroll
            for (int rt = 0; rt < 2; ++rt)
                #pragma unroll
                for (int j = 0; j < 4; ++j) p += smv[rt][j] * acc2[rt][ctl][j];
            p += __shfl_xor(p, 16);
            p += __shfl_xor(p, 32);
            if (q == 0) pool1[(wv * 4 + ctl) * 16 + r] = p;
        }
        #pragma unroll
        for (int rt = 0; rt < 2; ++rt)
            #pragma unroll
            for (int ctl = 0; ctl < 4; ++ctl)
                #pragma unroll
                for (int j = 0; j < 4; ++j) {
                    float v = acc2[rt][ctl][j];
                    int row = rt * 16 + q * 4 + j;
                    int ch = (wv * 4 + ctl) * 16 + r;
                    short h, l; bsplit(v, h, l);
                    int idx = row * 256 + (ch ^ ((row & 7) << 3));
                    x2h[idx] = h; x2l[idx] = l;
                }
    }
    __syncthreads();

    // ---- fg = pool1 @ mw1^T + mb1 ----
    {
        float a0 = mb1[t];
        for (int c = 0; c < 256; ++c) a0 += pool1[c] * mw1T[c * 256 + t];
        fgs[t] = a0;
    }
    __syncthreads();

    // ---- fgpart[o] = b3[o] + sum_{c<256} fg[c]*w3[o][c] ----
    {
        float f0 = b3[t], f1 = b3[t + 256];
        for (int c = 0; c < 256; ++c) {
            float fv = fgs[c];
            f0 += fv * w3fgT[c * 512 + t];
            f1 += fv * w3fgT[c * 512 + t + 256];
        }
        fgpart[t] = f0; fgpart[t + 256] = f1;
    }
    __syncthreads();

    // ---- conv3 via MFMA (M=32, N=512, K=256), bf16x3; C-init = fgpart ----
    f32x4 acc3[2][8];
    #pragma unroll
    for (int rt = 0; rt < 2; ++rt)
        #pragma unroll
        for (int ctl = 0; ctl < 8; ++ctl) {
            float fp = fgpart[(wv * 8 + ctl) * 16 + r];
            acc3[rt][ctl] = (f32x4){fp, fp, fp, fp};
        }
    for (int ks = 0; ks < 8; ++ks) {
        bf16x8 ah[2], al[2];
        #pragma unroll
        for (int rt = 0; rt < 2; ++rt) {
            int row = rt * 16 + r;
            int kk = ks * 32 + q * 8;
            int idx = row * 256 + (kk ^ ((row & 7) << 3));
            ah[rt] = *(const bf16x8*)(x2h + idx);
            al[rt] = *(const bf16x8*)(x2l + idx);
        }
        #pragma unroll
        for (int ctl = 0; ctl < 8; ++ctl) {
            int ct = wv * 8 + ctl;
            size_t woff = ((size_t)(ct * 8 + ks) * 64 + lane) * 8;
            bf16x8 bh = *(const bf16x8*)(w3fh + woff);
            bf16x8 bl = *(const bf16x8*)(w3fl + woff);
            #pragma unroll
            for (int rt = 0; rt < 2; ++rt) {
                acc3[rt][ctl] = MFMA16(al[rt], bh, acc3[rt][ctl]);
                acc3[rt][ctl] = MFMA16(ah[rt], bl, acc3[rt][ctl]);
                acc3[rt][ctl] = MFMA16(ah[rt], bh, acc3[rt][ctl]);
            }
        }
    }

    // ---- BN + ReLU in regs; attn2 scores via u-collapse ----
    float uv[8];
    {
        #pragma unroll
        for (int ctl = 0; ctl < 8; ++ctl) {
            int ch = (wv * 8 + ctl) * 16 + r;
            float s = sc2[ch], sh = sh2[ch];
            uv[ctl] = u[ch];
            #pragma unroll
            for (int rt = 0; rt < 2; ++rt)
                #pragma unroll
                for (int j = 0; j < 4; ++j)
                    acc3[rt][ctl][j] = fmaxf(acc3[rt][ctl][j] * s + sh, 0.f);
        }
        float sco[2][4];
        #pragma unroll
        for (int rt = 0; rt < 2; ++rt)
            #pragma unroll
            for (int j = 0; j < 4; ++j) {
                float s = 0.f;
                #pragma unroll
                for (int ctl = 0; ctl < 8; ++ctl) s += uv[ctl] * acc3[rt][ctl][j];
                sco[rt][j] = s;
            }
        #pragma unroll
        for (int off = 1; off < 16; off <<= 1)
            #pragma unroll
            for (int rt = 0; rt < 2; ++rt)
                #pragma unroll
                for (int j = 0; j < 4; ++j) sco[rt][j] += __shfl_xor(sco[rt][j], off);
        if (r == 0) {
            #pragma unroll
            for (int rt = 0; rt < 2; ++rt)
                #pragma unroll
                for (int j = 0; j < 4; ++j)
                    wred[wv * 32 + rt * 16 + q * 4 + j] = sco[rt][j];
        }
    }
    __syncthreads();
    if (t < 32) scs[t] = wred[t] + wred[32 + t] + wred[64 + t] + wred[96 + t] + ubp[0];
    __syncthreads();
    if (t < 32) {
        float mx = -INFINITY;
        for (int k = 0; k < 32; ++k) mx = fmaxf(mx, scs[k]);
        float ssum = 0.f;
        for (int k = 0; k < 32; ++k) ssum += expf(scs[k] - mx);
        sms[t] = expf(scs[t] - mx) / ssum;
    }
    __syncthreads();

    // ---- y = sum_k s[k]*x4[k,:] ----
    {
        float smv[2][4];
        #pragma unroll
        for (int rt = 0; rt < 2; ++rt)
            #pragma unroll
            for (int j = 0; j < 4; ++j) smv[rt][j] = sms[rt * 16 + q * 4 + j];
        #pragma unroll
        for (int ctl = 0; ctl < 8; ++ctl) {
            float p = 0.f;
            #pragma unroll
            for (int rt = 0; rt < 2; ++rt)
                #pragma unroll
                for (int j = 0; j < 4; ++j) p += smv[rt][j] * acc3[rt][ctl][j];
            p += __shfl_xor(p, 16);
            p += __shfl_xor(p, 32);
            if (q == 0) yvv[(wv * 8 + ctl) * 16 + r] = p;
        }
    }
    __syncthreads();

    // ---- fg2 = bb + y @ MT ----
    {
        float q0 = bb[t], q1 = bb[t + 256];
        for (int c = 0; c < 512; ++c) {
            float yc = yvv[c];
            q0 += yc * MT[c * 512 + t];
            q1 += yc * MT[c * 512 + t + 256];
        }
        out_fg2[(size_t)g * 512 + t] = q0;
        out_fg2[(size_t)g * 512 + t + 256] = q1;
    }
}

extern "C" void kernel_launch(void* const* d_in, const int* in_sizes, int n_in,
                              void* d_out, int out_size, void* d_ws, size_t ws_size,
                              hipStream_t stream) {
    const float* xyz  = (const float*)d_in[0];
    const int*   cidx = (const int*)d_in[1];
    const float* w1   = (const float*)d_in[2];
    const float* b1   = (const float*)d_in[3];
    const float* g1   = (const float*)d_in[4];
    const float* be1  = (const float*)d_in[5];
    const float* m1   = (const float*)d_in[6];
    const float* v1   = (const float*)d_in[7];
    const float* w2   = (const float*)d_in[8];
    const float* b2   = (const float*)d_in[9];
    const float* sw1  = (const float*)d_in[10];
    const float* sb1  = (const float*)d_in[11];
    const float* mw1  = (const float*)d_in[12];
    const float* mb1  = (const float*)d_in[13];
    const float* w3   = (const float*)d_in[14];
    const float* b3   = (const float*)d_in[15];
    const float* g2   = (const float*)d_in[16];
    const float* be2  = (const float*)d_in[17];
    const float* m2   = (const float*)d_in[18];
    const float* v2   = (const float*)d_in[19];
    const float* w4   = (const float*)d_in[20];
    const float* b4   = (const float*)d_in[21];
    const float* sw2  = (const float*)d_in[22];
    const float* sb2  = (const float*)d_in[23];
    const float* mw2  = (const float*)d_in[24];
    const float* mb2  = (const float*)d_in[25];

    float* out = (float*)d_out;
    char* ws = (char*)d_ws;
    int*   knn_idx = (int*)(ws + 0);            // 524288
    float* w3fgT = (float*)(ws + 524288);       // 524288
    float* mw1T  = (float*)(ws + 1048576);      // 262144
    float* MT    = (float*)(ws + 1310720);      // 1048576
    short* w2fh  = (short*)(ws + 2359296);      // 65536
    short* w2fl  = (short*)(ws + 2424832);      // 65536
    short* w3fh  = (short*)(ws + 2490368);      // 262144
    short* w3fl  = (short*)(ws + 2752512);      // 262144
    float* sc1   = (float*)(ws + 3014656);      // 512
    float* sh1   = (float*)(ws + 3015168);      // 512
    float* sc2   = (float*)(ws + 3015680);      // 2048
    float* sh2   = (float*)(ws + 3017728);      // 2048
    float* u     = (float*)(ws + 3019776);      // 2048
    float* bb    = (float*)(ws + 3021824);      // 2048
    float* ub    = (float*)(ws + 3023872);      // 4

    prep_misc<<<256, 256, 0, stream>>>(w1, g1, be1, m1, v1, w2, mw1, w3,
                                       g2, be2, m2, v2, w4, sw2, b4, sb2, mw2, mb2,
                                       w3fgT, mw1T, w2fh, w2fl, w3fh, w3fl,
                                       sc1, sh1, sc2, sh2, u, bb, ub);
    prep_mgemm<<<512, 256, 0, stream>>>(mw2, w4, MT);
    knn_kernel<<<4096, 256, 0, stream>>>(xyz, cidx, knn_idx, out);
    mlp_kernel<<<4096, 256, 0, stream>>>(xyz, cidx, knn_idx,
                                         w1, b1, sc1, sh1, w2fh, w2fl, b2,
                                         sw1, sb1, mw1T, mb1,
                                         w3fgT, b3, sc2, sh2, w3fh, w3fl,
                                         u, ub, MT, bb,
                                         out + 12288);
}

// Round 3
// 459.507 us; speedup vs baseline: 3.5570x; 1.8155x over previous
//
#include <hip/hip_runtime.h>
#include <math.h>

#define EPSV 1e-5f

typedef __attribute__((ext_vector_type(8))) short bf16x8;
typedef __attribute__((ext_vector_type(4))) float f32x4;

#define MFMA16(a, b, c) __builtin_amdgcn_mfma_f32_16x16x32_bf16(a, b, c, 0, 0, 0)

__device__ __forceinline__ short f2bf(float x) {
    unsigned u = __float_as_uint(x);
    unsigned r = (u + 0x7fffu + ((u >> 16) & 1u)) >> 16;
    return (short)r;
}
__device__ __forceinline__ float bf2f(short h) {
    return __uint_as_float(((unsigned)(unsigned short)h) << 16);
}
__device__ __forceinline__ void bsplit(float x, short& h, short& l) {
    h = f2bf(x);
    l = f2bf(x - bf2f(h));
}

// ---------------- prep_misc: frag packing, BN folds, u/bb/ub/bc3 -------------
__global__ __launch_bounds__(256) void prep_misc(
    const float* __restrict__ g1, const float* __restrict__ be1,
    const float* __restrict__ m1, const float* __restrict__ v1,
    const float* __restrict__ w2,
    const float* __restrict__ w3, const float* __restrict__ b3,
    const float* __restrict__ g2, const float* __restrict__ be2,
    const float* __restrict__ m2, const float* __restrict__ v2,
    const float* __restrict__ w4, const float* __restrict__ sw2,
    const float* __restrict__ b4, const float* __restrict__ sb2,
    const float* __restrict__ mw2, const float* __restrict__ mb2,
    const float* __restrict__ mb1,
    short* __restrict__ w2fh, short* __restrict__ w2fl,
    short* __restrict__ w3fh, short* __restrict__ w3fl,
    float* __restrict__ sc1, float* __restrict__ sh1,
    float* __restrict__ sc2, float* __restrict__ sh2,
    float* __restrict__ u, float* __restrict__ bb, float* __restrict__ ub,
    float* __restrict__ bc3)
{
    int tid = blockIdx.x * blockDim.x + threadIdx.x;
    int nthr = gridDim.x * blockDim.x;
    // w2 fragments: value = w2[o=ct*16+(lane&15)][k=ks*32+(lane>>4)*8+j]
    for (int i = tid; i < 32768; i += nthr) {
        int j = i & 7, lane = (i >> 3) & 63, rest = i >> 9;
        int ks = rest & 3, ct = rest >> 2;
        int o = ct * 16 + (lane & 15);
        int k = ks * 32 + (lane >> 4) * 8 + j;
        short h, l; bsplit(w2[o * 128 + k], h, l);
        w2fh[i] = h; w2fl[i] = l;
    }
    // w3 fragments (c in [256,512)): value = w3[o=ct*16+(lane&15)][256+ks*32+(lane>>4)*8+j]
    for (int i = tid; i < 131072; i += nthr) {
        int j = i & 7, lane = (i >> 3) & 63, rest = i >> 9;
        int ks = rest & 7, ct = rest >> 3;
        int o = ct * 16 + (lane & 15);
        int c = 256 + ks * 32 + (lane >> 4) * 8 + j;
        short h, l; bsplit(w3[o * 512 + c], h, l);
        w3fh[i] = h; w3fl[i] = l;
    }
    for (int i = tid; i < 128; i += nthr) {
        float s = g1[i] * rsqrtf(v1[i] + EPSV);
        sc1[i] = s; sh1[i] = be1[i] - m1[i] * s;
    }
    for (int i = tid; i < 512; i += nthr) {
        float s = g2[i] * rsqrtf(v2[i] + EPSV);
        sc2[i] = s; sh2[i] = be2[i] - m2[i] * s;
    }
    // u[c] = sum_o sw2[o]*w4[o][c]
    for (int c = tid; c < 512; c += nthr) {
        float acc = 0.f;
        for (int o = 0; o < 512; ++o) acc += sw2[o] * w4[o * 512 + c];
        u[c] = acc;
    }
    // bb[q] = mb2[q] + sum_o mw2[q][o]*b4[o]
    for (int qq = tid; qq < 512; qq += nthr) {
        float acc = mb2[qq];
        for (int o = 0; o < 512; ++o) acc += mw2[qq * 512 + o] * b4[o];
        bb[qq] = acc;
    }
    // bc3[o] = b3[o] + sum_d mb1[d]*w3[o][d], d<256
    for (int o = tid; o < 512; o += nthr) {
        float acc = b3[o];
        for (int d = 0; d < 256; ++d) acc += mb1[d] * w3[o * 512 + d];
        bc3[o] = acc;
    }
    if (tid == 0) {
        float acc = sb2[0];
        for (int o = 0; o < 512; ++o) acc += sw2[o] * b4[o];
        ub[0] = acc;
    }
}

// ---------------- prep_P: P[c][o] = sum_d mw1[d][c]*w3[o][d] (d,c<256) ------
__global__ __launch_bounds__(256) void prep_P(
    const float* __restrict__ mw1, const float* __restrict__ w3,
    float* __restrict__ P)
{
    __shared__ float col[256];
    int c = blockIdx.x, t = threadIdx.x;
    col[t] = mw1[t * 256 + c];
    __syncthreads();
    for (int oo = t; oo < 512; oo += 256) {
        float acc = 0.f;
        for (int d = 0; d < 256; ++d) acc += col[d] * w3[oo * 512 + d];
        P[c * 512 + oo] = acc;
    }
}

// ---------------- prep_MT: MT[c][q] = sum_o mw2[q][o]*w4[o][c] ---------------
__global__ __launch_bounds__(256) void prep_MT(
    const float* __restrict__ mw2, const float* __restrict__ w4,
    float* __restrict__ MT)
{
    __shared__ float row[512];
    int qq = blockIdx.x, t = threadIdx.x;
    row[t] = mw2[qq * 512 + t];
    row[t + 256] = mw2[qq * 512 + t + 256];
    __syncthreads();
    float a0 = 0.f, a1 = 0.f;
    for (int o = 0; o < 512; ++o) {
        float m = row[o];
        a0 += m * w4[o * 512 + t];
        a1 += m * w4[o * 512 + t + 256];
    }
    MT[t * 512 + qq] = a0;
    MT[(t + 256) * 512 + qq] = a1;
}

// ---------------- prep_MTpack: MT -> bf16 h/l fragments ----------------------
__global__ __launch_bounds__(256) void prep_MTpack(
    const float* __restrict__ MT,
    short* __restrict__ MTfh, short* __restrict__ MTfl)
{
    int tid = blockIdx.x * blockDim.x + threadIdx.x;
    int nthr = gridDim.x * blockDim.x;
    // layout [ct=32][ks=16][lane][j]: val = MT[k=ks*32+(lane>>4)*8+j][n=ct*16+(lane&15)]
    for (int i = tid; i < 262144; i += nthr) {
        int j = i & 7, lane = (i >> 3) & 63, rest = i >> 9;
        int ks = rest & 15, ct = rest >> 4;
        int k = ks * 32 + (lane >> 4) * 8 + j;
        int n = ct * 16 + (lane & 15);
        short h, l; bsplit(MT[k * 512 + n], h, l);
        MTfh[i] = h; MTfl[i] = l;
    }
}

// ---------------- KNN: threshold + exact lex-rank select ---------------------
#define KCAP 2048
__global__ __launch_bounds__(256) void knn_kernel(
    const float* __restrict__ xyz, const int* __restrict__ cidx,
    int* __restrict__ knn_idx, float* __restrict__ out_center)
{
    __shared__ unsigned cu[KCAP];
    __shared__ unsigned short cix[KCAP];
    __shared__ unsigned Tws[4];
    __shared__ unsigned cntS;
    int g = blockIdx.x;
    int b = g >> 9;
    int t = threadIdx.x;
    int lane = t & 63, w = t >> 6;
    const float* xb = xyz + (size_t)b * 8192 * 3;
    int ci = cidx[g];
    float cx = xb[ci * 3 + 0], cy = xb[ci * 3 + 1], cz = xb[ci * 3 + 2];
    float c2 = cx * cx + cy * cy + cz * cz;
    if (t < 3) out_center[g * 3 + t] = xb[ci * 3 + t];
    if (t == 0) cntS = 0;

    unsigned ue[32];
    unsigned vmin = 0xffffffffu;
    #pragma unroll
    for (int i = 0; i < 32; ++i) {
        int n = t + (i << 8);
        float x = xb[n * 3 + 0], y = xb[n * 3 + 1], z = xb[n * 3 + 2];
        float n2 = x * x + y * y + z * z;
        float d = c2 + n2 - 2.f * (cx * x + cy * y + cz * z);
        unsigned uu = __float_as_uint(d);
        uu = (uu & 0x80000000u) ? ~uu : (uu | 0x80000000u);
        ue[i] = uu;
        vmin = min(vmin, uu);
    }
    // wave bitonic sort of 64 thread-mins (values only)
    unsigned v = vmin;
    #pragma unroll
    for (int k = 2; k <= 64; k <<= 1) {
        #pragma unroll
        for (int jj = k >> 1; jj > 0; jj >>= 1) {
            unsigned o = __shfl_xor(v, jj);
            bool dir_asc = ((lane & k) == 0) || (k == 64);
            bool lower = (lane & jj) == 0;
            bool take_min = (lower == dir_asc);
            unsigned mn = min(v, o), mx = max(v, o);
            v = take_min ? mn : mx;
        }
    }
    unsigned Tw = __shfl(v, 31);   // 32nd smallest of wave's thread-mins
    if (lane == 0) Tws[w] = Tw;
    __syncthreads();
    unsigned T = min(min(Tws[0], Tws[1]), min(Tws[2], Tws[3]));

    // collect candidates <= T
    #pragma unroll
    for (int i = 0; i < 32; ++i) {
        if (ue[i] <= T) {
            unsigned pos = atomicAdd(&cntS, 1u);
            if (pos < KCAP) {
                cu[pos] = ue[i];
                cix[pos] = (unsigned short)(t + (i << 8));
            }
        }
    }
    __syncthreads();
    int C = (int)min(cntS, (unsigned)KCAP);
    // exact rank by (value, index): rank < 32 selected
    for (int cc = t; cc < C; cc += 256) {
        unsigned uc = cu[cc];
        unsigned short icd = cix[cc];
        int rank = 0;
        for (int j = 0; j < C; ++j) {
            unsigned uj = cu[j];
            rank += (uj < uc) || (uj == uc && cix[j] < icd);
        }
        if (rank < 32) knn_idx[g * 32 + rank] = (int)icd;
    }
}

// ---------------- fused per-group MLP (4 groups/block, 512 threads) ----------
__global__ __launch_bounds__(512) void mlp_kernel(
    const float* __restrict__ xyz, const int* __restrict__ cidx,
    const int* __restrict__ knn_idx,
    const float* __restrict__ w1, const float* __restrict__ b1,
    const float* __restrict__ sc1, const float* __restrict__ sh1,
    const short* __restrict__ w2fh, const short* __restrict__ w2fl,
    const float* __restrict__ b2,
    const float* __restrict__ sw1, const float* __restrict__ sb1,
    const float* __restrict__ P, const float* __restrict__ bc3,
    const short* __restrict__ w3fh, const short* __restrict__ w3fl,
    const float* __restrict__ sc2, const float* __restrict__ sh2,
    const float* __restrict__ u, const float* __restrict__ ubp,
    short* __restrict__ yh)
{
    __shared__ __align__(16) char smem[78848];
    short* x1 = (short*)smem;                   // [128][128] bf16 swizzled
    short* x2 = (short*)smem;                   // [128][256] bf16 swizzled (overlays x1)
    float* feat = (float*)(smem + 32768);       // [128][12] (temp, inside x2 hi half)
    float* cen  = (float*)(smem + 38912);       // [4][3]
    float* scs  = (float*)(smem + 65536);       // [128]
    float* sms  = (float*)(smem + 66048);       // [128]
    float* pool1 = (float*)(smem + 66560);      // [4][256]
    float* fgpart = (float*)(smem + 70656);     // [4][512]

    int gb = blockIdx.x * 4;
    int bq = gb >> 9;
    int t = threadIdx.x;
    int lane = t & 63, wv = t >> 6, q = lane >> 4, r = lane & 15;
    const float* xb = xyz + (size_t)bq * 8192 * 3;

    // P0: centers + scs init
    if (t < 4) {
        int ci = cidx[gb + t];
        cen[t * 3 + 0] = xb[ci * 3 + 0];
        cen[t * 3 + 1] = xb[ci * 3 + 1];
        cen[t * 3 + 2] = xb[ci * 3 + 2];
    }
    if (t < 128) scs[t] = sb1[0];
    __syncthreads();

    // P1: feat gather (t<128 rows)
    if (t < 128) {
        int gg = t >> 5, kk = t & 31;
        int n = knn_idx[(gb + gg) * 32 + kk];
        float cxx = cen[gg * 3 + 0], cyy = cen[gg * 3 + 1], czz = cen[gg * 3 + 2];
        float nx = xb[n * 3 + 0], ny = xb[n * 3 + 1], nz = xb[n * 3 + 2];
        float rx = cxx - nx, ry = cyy - ny, rz = czz - nz;
        float rd = sqrtf(rx * rx + ry * ry + rz * rz);
        float* fr = feat + t * 12;
        fr[0] = rd; fr[1] = rx; fr[2] = ry; fr[3] = rz;
        fr[4] = cxx; fr[5] = cyy; fr[6] = czz;
        fr[7] = nx; fr[8] = ny; fr[9] = nz;
    }
    __syncthreads();

    // P2: conv1 + BN + ReLU -> x1 bf16 (swizzled)
    for (int i = 0; i < 32; ++i) {
        int flat = t + (i << 9);
        int row = flat >> 7, o = flat & 127;
        const float* wr = w1 + o * 10;
        const float* fr = feat + row * 12;
        float acc = b1[o];
        #pragma unroll
        for (int c = 0; c < 10; ++c) acc += fr[c] * wr[c];
        acc = fmaxf(acc * sc1[o] + sh1[o], 0.f);
        x1[row * 128 + (o ^ ((row & 7) << 3))] = f2bf(acc);
    }
    __syncthreads();

    // P3: conv2 via MFMA: M=128, N=256 (wave: 2 ct), K=128
    f32x4 acc2[8][2];
    #pragma unroll
    for (int rt = 0; rt < 8; ++rt)
        #pragma unroll
        for (int ctl = 0; ctl < 2; ++ctl) {
            float bv = b2[(wv * 2 + ctl) * 16 + r];
            acc2[rt][ctl] = (f32x4){bv, bv, bv, bv};
        }
    #pragma unroll
    for (int ks = 0; ks < 4; ++ks) {
        bf16x8 af[8];
        #pragma unroll
        for (int rt = 0; rt < 8; ++rt) {
            int row = rt * 16 + r;
            int kk = ks * 32 + q * 8;
            af[rt] = *(const bf16x8*)(x1 + row * 128 + (kk ^ ((row & 7) << 3)));
        }
        #pragma unroll
        for (int ctl = 0; ctl < 2; ++ctl) {
            int ct = wv * 2 + ctl;
            size_t woff = ((size_t)(ct * 4 + ks) * 64 + lane) * 8;
            bf16x8 bh = *(const bf16x8*)(w2fh + woff);
            bf16x8 bl = *(const bf16x8*)(w2fl + woff);
            #pragma unroll
            for (int rt = 0; rt < 8; ++rt) {
                acc2[rt][ctl] = MFMA16(af[rt], bl, acc2[rt][ctl]);
                acc2[rt][ctl] = MFMA16(af[rt], bh, acc2[rt][ctl]);
            }
        }
    }
    // attn1 score partials: s[row] += sum_ch sw1[ch]*x2[row][ch]
    {
        float sw1v[2];
        #pragma unroll
        for (int ctl = 0; ctl < 2; ++ctl) sw1v[ctl] = sw1[(wv * 2 + ctl) * 16 + r];
        #pragma unroll
        for (int rt = 0; rt < 8; ++rt)
            #pragma unroll
            for (int j = 0; j < 4; ++j) {
                float s = sw1v[0] * acc2[rt][0][j] + sw1v[1] * acc2[rt][1][j];
                s += __shfl_xor(s, 1); s += __shfl_xor(s, 2);
                s += __shfl_xor(s, 4); s += __shfl_xor(s, 8);
                if (r == 0) atomicAdd(&scs[rt * 16 + q * 4 + j], s);
            }
    }
    __syncthreads();

    // P4: softmax1 + x2 store (bf16, swizzled; overlays x1 - dead)
    if (t < 128) {
        int gg = t >> 5;
        float mx = -INFINITY;
        for (int k = 0; k < 32; ++k) mx = fmaxf(mx, scs[gg * 32 + k]);
        float ssum = 0.f;
        for (int k = 0; k < 32; ++k) ssum += expf(scs[gg * 32 + k] - mx);
        sms[t] = expf(scs[t] - mx) / ssum;
    }
    #pragma unroll
    for (int rt = 0; rt < 8; ++rt)
        #pragma unroll
        for (int ctl = 0; ctl < 2; ++ctl) {
            int ch = (wv * 2 + ctl) * 16 + r;
            #pragma unroll
            for (int j = 0; j < 4; ++j) {
                int row = rt * 16 + q * 4 + j;
                x2[row * 256 + (ch ^ ((row & 7) << 3))] = f2bf(acc2[rt][ctl][j]);
            }
        }
    __syncthreads();

    // P5: pool1 from acc2 + sms; re-init scs for attn2
    {
        #pragma unroll
        for (int ctl = 0; ctl < 2; ++ctl)
            #pragma unroll
            for (int gg = 0; gg < 4; ++gg) {
                float p = 0.f;
                #pragma unroll
                for (int rr = 0; rr < 2; ++rr) {
                    int rt = gg * 2 + rr;
                    #pragma unroll
                    for (int j = 0; j < 4; ++j)
                        p += sms[rt * 16 + q * 4 + j] * acc2[rt][ctl][j];
                }
                p += __shfl_xor(p, 16);
                p += __shfl_xor(p, 32);
                if (q == 0) pool1[gg * 256 + (wv * 2 + ctl) * 16 + r] = p;
            }
    }
    __syncthreads();
    if (t < 128) scs[t] = ubp[0];

    // P6: fgpart[g][o] = bc3[o] + pool1[g] @ P[:, o]
    {
        float f0 = bc3[t], f1 = f0, f2 = f0, f3 = f0;
        // separate accumulators per group, shared bc3 base
        float a0 = 0.f, a1 = 0.f, a2 = 0.f, a3 = 0.f;
        for (int c = 0; c < 256; ++c) {
            float pv = P[c * 512 + t];
            a0 += pool1[c] * pv;
            a1 += pool1[256 + c] * pv;
            a2 += pool1[512 + c] * pv;
            a3 += pool1[768 + c] * pv;
        }
        fgpart[t] = f0 + a0;
        fgpart[512 + t] = f1 + a1;
        fgpart[1024 + t] = f2 + a2;
        fgpart[1536 + t] = f3 + a3;
    }
    __syncthreads();

    // P7: conv3 via MFMA: M=128, N=512 (wave: 4 ct), K=256; C-init = fgpart
    f32x4 acc3[8][4];
    #pragma unroll
    for (int rt = 0; rt < 8; ++rt) {
        int gg = rt >> 1;
        #pragma unroll
        for (int ctl = 0; ctl < 4; ++ctl) {
            float fp = fgpart[gg * 512 + (wv * 4 + ctl) * 16 + r];
            acc3[rt][ctl] = (f32x4){fp, fp, fp, fp};
        }
    }
    #pragma unroll
    for (int ks = 0; ks < 8; ++ks) {
        bf16x8 af[8];
        #pragma unroll
        for (int rt = 0; rt < 8; ++rt) {
            int row = rt * 16 + r;
            int kk = ks * 32 + q * 8;
            af[rt] = *(const bf16x8*)(x2 + row * 256 + (kk ^ ((row & 7) << 3)));
        }
        #pragma unroll
        for (int ctl = 0; ctl < 4; ++ctl) {
            int ct = wv * 4 + ctl;
            size_t woff = ((size_t)(ct * 8 + ks) * 64 + lane) * 8;
            bf16x8 bh = *(const bf16x8*)(w3fh + woff);
            bf16x8 bl = *(const bf16x8*)(w3fl + woff);
            #pragma unroll
            for (int rt = 0; rt < 8; ++rt) {
                acc3[rt][ctl] = MFMA16(af[rt], bl, acc3[rt][ctl]);
                acc3[rt][ctl] = MFMA16(af[rt], bh, acc3[rt][ctl]);
            }
        }
    }
    // BN2 + ReLU in regs; attn2 score partials via u-collapse
    float uv[4];
    {
        #pragma unroll
        for (int ctl = 0; ctl < 4; ++ctl) {
            int ch = (wv * 4 + ctl) * 16 + r;
            float s = sc2[ch], sh = sh2[ch];
            uv[ctl] = u[ch];
            #pragma unroll
            for (int rt = 0; rt < 8; ++rt)
                #pragma unroll
                for (int j = 0; j < 4; ++j)
                    acc3[rt][ctl][j] = fmaxf(acc3[rt][ctl][j] * s + sh, 0.f);
        }
        #pragma unroll
        for (int rt = 0; rt < 8; ++rt)
            #pragma unroll
            for (int j = 0; j < 4; ++j) {
                float s = uv[0] * acc3[rt][0][j] + uv[1] * acc3[rt][1][j]
                        + uv[2] * acc3[rt][2][j] + uv[3] * acc3[rt][3][j];
                s += __shfl_xor(s, 1); s += __shfl_xor(s, 2);
                s += __shfl_xor(s, 4); s += __shfl_xor(s, 8);
                if (r == 0) atomicAdd(&scs[rt * 16 + q * 4 + j], s);
            }
    }
    __syncthreads();

    // P8: softmax2
    if (t < 128) {
        int gg = t >> 5;
        float mx = -INFINITY;
        for (int k = 0; k < 32; ++k) mx = fmaxf(mx, scs[gg * 32 + k]);
        float ssum = 0.f;
        for (int k = 0; k < 32; ++k) ssum += expf(scs[gg * 32 + k] - mx);
        sms[t] = expf(scs[t] - mx) / ssum;
    }
    __syncthreads();

    // P9: y[g][ch] = sum_k s[k]*x4[k][ch] -> global bf16
    {
        #pragma unroll
        for (int ctl = 0; ctl < 4; ++ctl)
            #pragma unroll
            for (int gg = 0; gg < 4; ++gg) {
                float p = 0.f;
                #pragma unroll
                for (int rr = 0; rr < 2; ++rr) {
                    int rt = gg * 2 + rr;
                    #pragma unroll
                    for (int j = 0; j < 4; ++j)
                        p += sms[rt * 16 + q * 4 + j] * acc3[rt][ctl][j];
                }
                p += __shfl_xor(p, 16);
                p += __shfl_xor(p, 32);
                if (q == 0) {
                    int grow = gb + gg;
                    int ch = (wv * 4 + ctl) * 16 + r;
                    yh[(size_t)grow * 512 + ch] = f2bf(p);
                }
            }
    }
}

// ---------------- fg2 GEMM: out = bb + y @ MT (M=4096,N=512,K=512) -----------
__global__ __launch_bounds__(256) void fg2_kernel(
    const short* __restrict__ yh,
    const short* __restrict__ MTfh, const short* __restrict__ MTfl,
    const float* __restrict__ bb, float* __restrict__ out_fg2)
{
    int gbase = blockIdx.x * 32;
    int t = threadIdx.x;
    int lane = t & 63, wv = t >> 6, q = lane >> 4, r = lane & 15;
    f32x4 acc[2][8];
    #pragma unroll
    for (int rt = 0; rt < 2; ++rt)
        #pragma unroll
        for (int ctl = 0; ctl < 8; ++ctl) {
            float bv = bb[(wv * 8 + ctl) * 16 + r];
            acc[rt][ctl] = (f32x4){bv, bv, bv, bv};
        }
    #pragma unroll
    for (int ks = 0; ks < 16; ++ks) {
        bf16x8 af[2];
        #pragma unroll
        for (int rt = 0; rt < 2; ++rt) {
            int grow = gbase + rt * 16 + r;
            af[rt] = *(const bf16x8*)(yh + (size_t)grow * 512 + ks * 32 + q * 8);
        }
        #pragma unroll
        for (int ctl = 0; ctl < 8; ++ctl) {
            int ct = wv * 8 + ctl;
            size_t woff = ((size_t)(ct * 16 + ks) * 64 + lane) * 8;
            bf16x8 bh = *(const bf16x8*)(MTfh + woff);
            bf16x8 bl = *(const bf16x8*)(MTfl + woff);
            #pragma unroll
            for (int rt = 0; rt < 2; ++rt) {
                acc[rt][ctl] = MFMA16(af[rt], bl, acc[rt][ctl]);
                acc[rt][ctl] = MFMA16(af[rt], bh, acc[rt][ctl]);
            }
        }
    }
    #pragma unroll
    for (int rt = 0; rt < 2; ++rt)
        #pragma unroll
        for (int ctl = 0; ctl < 8; ++ctl) {
            int ch = (wv * 8 + ctl) * 16 + r;
            #pragma unroll
            for (int j = 0; j < 4; ++j) {
                int grow = gbase + rt * 16 + q * 4 + j;
                out_fg2[(size_t)grow * 512 + ch] = acc[rt][ctl][j];
            }
        }
}

extern "C" void kernel_launch(void* const* d_in, const int* in_sizes, int n_in,
                              void* d_out, int out_size, void* d_ws, size_t ws_size,
                              hipStream_t stream) {
    const float* xyz  = (const float*)d_in[0];
    const int*   cidx = (const int*)d_in[1];
    const float* w1   = (const float*)d_in[2];
    const float* b1   = (const float*)d_in[3];
    const float* g1   = (const float*)d_in[4];
    const float* be1  = (const float*)d_in[5];
    const float* m1   = (const float*)d_in[6];
    const float* v1   = (const float*)d_in[7];
    const float* w2   = (const float*)d_in[8];
    const float* b2   = (const float*)d_in[9];
    const float* sw1  = (const float*)d_in[10];
    const float* sb1  = (const float*)d_in[11];
    const float* mw1  = (const float*)d_in[12];
    const float* mb1  = (const float*)d_in[13];
    const float* w3   = (const float*)d_in[14];
    const float* b3   = (const float*)d_in[15];
    const float* g2   = (const float*)d_in[16];
    const float* be2  = (const float*)d_in[17];
    const float* m2   = (const float*)d_in[18];
    const float* v2   = (const float*)d_in[19];
    const float* w4   = (const float*)d_in[20];
    const float* b4   = (const float*)d_in[21];
    const float* sw2  = (const float*)d_in[22];
    const float* sb2  = (const float*)d_in[23];
    const float* mw2  = (const float*)d_in[24];
    const float* mb2  = (const float*)d_in[25];

    float* out = (float*)d_out;
    char* ws = (char*)d_ws;
    int*   knn_idx = (int*)(ws + 0);             // 524288
    short* w2fh = (short*)(ws + 524288);         // 65536
    short* w2fl = (short*)(ws + 589824);         // 65536
    short* w3fh = (short*)(ws + 655360);         // 262144
    short* w3fl = (short*)(ws + 917504);         // 262144
    float* P    = (float*)(ws + 1179648);        // 524288
    float* bc3  = (float*)(ws + 1703936);        // 2048
    float* sc1  = (float*)(ws + 1705984);        // 512
    float* sh1  = (float*)(ws + 1706496);        // 512
    float* sc2  = (float*)(ws + 1707008);        // 2048
    float* sh2  = (float*)(ws + 1709056);        // 2048
    float* u    = (float*)(ws + 1711104);        // 2048
    float* bb   = (float*)(ws + 1713152);        // 2048
    float* ub   = (float*)(ws + 1715200);        // 256 (pad)
    short* MTfh = (short*)(ws + 1715456);        // 524288
    short* MTfl = (short*)(ws + 2239744);        // 524288
    short* yh   = (short*)(ws + 2764032);        // 4194304
    float* MTf  = (float*)(ws + 2764032);        // 1048576 (overlays yh; dead before yh written)

    prep_misc<<<256, 256, 0, stream>>>(g1, be1, m1, v1, w2, w3, b3,
                                       g2, be2, m2, v2, w4, sw2, b4, sb2, mw2, mb2, mb1,
                                       w2fh, w2fl, w3fh, w3fl,
                                       sc1, sh1, sc2, sh2, u, bb, ub, bc3);
    prep_P<<<256, 256, 0, stream>>>(mw1, w3, P);
    prep_MT<<<512, 256, 0, stream>>>(mw2, w4, MTf);
    prep_MTpack<<<512, 256, 0, stream>>>(MTf, MTfh, MTfl);
    knn_kernel<<<4096, 256, 0, stream>>>(xyz, cidx, knn_idx, out);
    mlp_kernel<<<1024, 512, 0, stream>>>(xyz, cidx, knn_idx,
                                         w1, b1, sc1, sh1, w2fh, w2fl, b2,
                                         sw1, sb1, P, bc3, w3fh, w3fl,
                                         sc2, sh2, u, ub, yh);
    fg2_kernel<<<128, 256, 0, stream>>>(yh, MTfh, MTfl, bb, out + 12288);
}

// Round 4
// 444.062 us; speedup vs baseline: 3.6807x; 1.0348x over previous
//
#include <hip/hip_runtime.h>
#include <math.h>

#define EPSV 1e-5f

typedef __attribute__((ext_vector_type(8))) short bf16x8;
typedef __attribute__((ext_vector_type(4))) float f32x4;

#define MFMA16(a, b, c) __builtin_amdgcn_mfma_f32_16x16x32_bf16(a, b, c, 0, 0, 0)

__device__ __forceinline__ short f2bf(float x) {
    unsigned u = __float_as_uint(x);
    unsigned r = (u + 0x7fffu + ((u >> 16) & 1u)) >> 16;
    return (short)r;
}
__device__ __forceinline__ float bf2f(short h) {
    return __uint_as_float(((unsigned)(unsigned short)h) << 16);
}
__device__ __forceinline__ void bsplit(float x, short& h, short& l) {
    h = f2bf(x);
    l = f2bf(x - bf2f(h));
}

// ---------------- prep_misc: frag packing, BN folds, u/bb/ub/bc3 -------------
__global__ __launch_bounds__(256) void prep_misc(
    const float* __restrict__ g1, const float* __restrict__ be1,
    const float* __restrict__ m1, const float* __restrict__ v1,
    const float* __restrict__ w2,
    const float* __restrict__ w3, const float* __restrict__ b3,
    const float* __restrict__ g2, const float* __restrict__ be2,
    const float* __restrict__ m2, const float* __restrict__ v2,
    const float* __restrict__ w4, const float* __restrict__ sw2,
    const float* __restrict__ b4, const float* __restrict__ sb2,
    const float* __restrict__ mw2, const float* __restrict__ mb2,
    const float* __restrict__ mb1,
    short* __restrict__ w2fh, short* __restrict__ w2fl,
    short* __restrict__ w3fh, short* __restrict__ w3fl,
    float* __restrict__ sc1, float* __restrict__ sh1,
    float* __restrict__ sc2, float* __restrict__ sh2,
    float* __restrict__ u, float* __restrict__ bb, float* __restrict__ ub,
    float* __restrict__ bc3)
{
    int tid = blockIdx.x * blockDim.x + threadIdx.x;
    int nthr = gridDim.x * blockDim.x;
    // w2 fragments: value = w2[o=ct*16+(lane&15)][k=ks*32+(lane>>4)*8+j]
    for (int i = tid; i < 32768; i += nthr) {
        int j = i & 7, lane = (i >> 3) & 63, rest = i >> 9;
        int ks = rest & 3, ct = rest >> 2;
        int o = ct * 16 + (lane & 15);
        int k = ks * 32 + (lane >> 4) * 8 + j;
        short h, l; bsplit(w2[o * 128 + k], h, l);
        w2fh[i] = h; w2fl[i] = l;
    }
    // w3 fragments (c in [256,512)): value = w3[o=ct*16+(lane&15)][256+ks*32+(lane>>4)*8+j]
    for (int i = tid; i < 131072; i += nthr) {
        int j = i & 7, lane = (i >> 3) & 63, rest = i >> 9;
        int ks = rest & 7, ct = rest >> 3;
        int o = ct * 16 + (lane & 15);
        int c = 256 + ks * 32 + (lane >> 4) * 8 + j;
        short h, l; bsplit(w3[o * 512 + c], h, l);
        w3fh[i] = h; w3fl[i] = l;
    }
    for (int i = tid; i < 128; i += nthr) {
        float s = g1[i] * rsqrtf(v1[i] + EPSV);
        sc1[i] = s; sh1[i] = be1[i] - m1[i] * s;
    }
    for (int i = tid; i < 512; i += nthr) {
        float s = g2[i] * rsqrtf(v2[i] + EPSV);
        sc2[i] = s; sh2[i] = be2[i] - m2[i] * s;
    }
    // u[c] = sum_o sw2[o]*w4[o][c]
    for (int c = tid; c < 512; c += nthr) {
        float acc = 0.f;
        for (int o = 0; o < 512; ++o) acc += sw2[o] * w4[o * 512 + c];
        u[c] = acc;
    }
    // bb[q] = mb2[q] + sum_o mw2[q][o]*b4[o]
    for (int qq = tid; qq < 512; qq += nthr) {
        float acc = mb2[qq];
        for (int o = 0; o < 512; ++o) acc += mw2[qq * 512 + o] * b4[o];
        bb[qq] = acc;
    }
    // bc3[o] = b3[o] + sum_d mb1[d]*w3[o][d], d<256
    for (int o = tid; o < 512; o += nthr) {
        float acc = b3[o];
        for (int d = 0; d < 256; ++d) acc += mb1[d] * w3[o * 512 + d];
        bc3[o] = acc;
    }
    if (tid == 0) {
        float acc = sb2[0];
        for (int o = 0; o < 512; ++o) acc += sw2[o] * b4[o];
        ub[0] = acc;
    }
}

// ---- prep_P: P[c][o] = sum_d mw1[d][c]*w3[o][d] -> bf16 h/l fragments -------
__global__ __launch_bounds__(256) void prep_P(
    const float* __restrict__ mw1, const float* __restrict__ w3,
    short* __restrict__ Pfh, short* __restrict__ Pfl)
{
    __shared__ float col[256];
    int c = blockIdx.x, t = threadIdx.x;
    col[t] = mw1[t * 256 + c];
    __syncthreads();
    int ks = c >> 5, qq = (c >> 3) & 3, jj = c & 7;
    for (int oo = t; oo < 512; oo += 256) {
        float acc = 0.f;
        for (int d = 0; d < 256; ++d) acc += col[d] * w3[oo * 512 + d];
        int ct = oo >> 4;
        size_t idx = ((size_t)(ct * 8 + ks) * 64 + qq * 16 + (oo & 15)) * 8 + jj;
        short h, l; bsplit(acc, h, l);
        Pfh[idx] = h; Pfl[idx] = l;
    }
}

// ---------------- prep_MT: MT[c][q] = sum_o mw2[q][o]*w4[o][c] ---------------
__global__ __launch_bounds__(256) void prep_MT(
    const float* __restrict__ mw2, const float* __restrict__ w4,
    float* __restrict__ MT)
{
    __shared__ float row[512];
    int qq = blockIdx.x, t = threadIdx.x;
    row[t] = mw2[qq * 512 + t];
    row[t + 256] = mw2[qq * 512 + t + 256];
    __syncthreads();
    float a0 = 0.f, a1 = 0.f;
    for (int o = 0; o < 512; ++o) {
        float m = row[o];
        a0 += m * w4[o * 512 + t];
        a1 += m * w4[o * 512 + t + 256];
    }
    MT[t * 512 + qq] = a0;
    MT[(t + 256) * 512 + qq] = a1;
}

// ---------------- prep_MTpack: MT -> bf16 h/l fragments ----------------------
__global__ __launch_bounds__(256) void prep_MTpack(
    const float* __restrict__ MT,
    short* __restrict__ MTfh, short* __restrict__ MTfl)
{
    int tid = blockIdx.x * blockDim.x + threadIdx.x;
    int nthr = gridDim.x * blockDim.x;
    for (int i = tid; i < 262144; i += nthr) {
        int j = i & 7, lane = (i >> 3) & 63, rest = i >> 9;
        int ks = rest & 15, ct = rest >> 4;
        int k = ks * 32 + (lane >> 4) * 8 + j;
        int n = ct * 16 + (lane & 15);
        short h, l; bsplit(MT[k * 512 + n], h, l);
        MTfh[i] = h; MTfl[i] = l;
    }
}

// ---------------- KNN: float4 loads + threshold + exact lex-rank -------------
#define KCAP 2048
__global__ __launch_bounds__(256) void knn_kernel(
    const float* __restrict__ xyz, const int* __restrict__ cidx,
    int* __restrict__ knn_idx, float* __restrict__ out_center)
{
    __shared__ unsigned cu[KCAP];
    __shared__ unsigned short cix[KCAP];
    __shared__ unsigned Tws[4];
    __shared__ unsigned cntS;
    int g = blockIdx.x;
    int b = g >> 9;
    int t = threadIdx.x;
    int lane = t & 63, w = t >> 6;
    const float* xb = xyz + (size_t)b * 8192 * 3;
    int ci = cidx[g];
    float cx = xb[ci * 3 + 0], cy = xb[ci * 3 + 1], cz = xb[ci * 3 + 2];
    float c2 = cx * cx + cy * cy + cz * cz;
    if (t < 3) out_center[g * 3 + t] = xb[ci * 3 + t];
    if (t == 0) cntS = 0;

    // distances for 32 contiguous points per thread via float4 loads
    const float4* p4 = (const float4*)xb + (size_t)t * 24;
    unsigned ue[32];
    unsigned vmin = 0xffffffffu;
    #pragma unroll
    for (int ii = 0; ii < 8; ++ii) {
        float4 v0 = p4[ii * 3 + 0];
        float4 v1 = p4[ii * 3 + 1];
        float4 v2 = p4[ii * 3 + 2];
        float px[4], py[4], pz[4];
        px[0] = v0.x; py[0] = v0.y; pz[0] = v0.z;
        px[1] = v0.w; py[1] = v1.x; pz[1] = v1.y;
        px[2] = v1.z; py[2] = v1.w; pz[2] = v2.x;
        px[3] = v2.y; py[3] = v2.z; pz[3] = v2.w;
        #pragma unroll
        for (int m = 0; m < 4; ++m) {
            float dx = px[m], dy = py[m], dz = pz[m];
            float n2 = dx * dx + dy * dy + dz * dz;
            float d = c2 + n2 - 2.f * (cx * dx + cy * dy + cz * dz);
            unsigned uu = __float_as_uint(d);
            uu = (uu & 0x80000000u) ? ~uu : (uu | 0x80000000u);
            ue[ii * 4 + m] = uu;
            vmin = min(vmin, uu);
        }
    }
    // wave bitonic sort of 64 thread-mins (values only)
    unsigned v = vmin;
    #pragma unroll
    for (int k = 2; k <= 64; k <<= 1) {
        #pragma unroll
        for (int jj = k >> 1; jj > 0; jj >>= 1) {
            unsigned o = __shfl_xor(v, jj);
            bool dir_asc = ((lane & k) == 0) || (k == 64);
            bool lower = (lane & jj) == 0;
            bool take_min = (lower == dir_asc);
            unsigned mn = min(v, o), mx = max(v, o);
            v = take_min ? mn : mx;
        }
    }
    unsigned Tw = __shfl(v, 31);   // 32nd smallest of wave's thread-mins
    if (lane == 0) Tws[w] = Tw;
    __syncthreads();
    unsigned T = min(min(Tws[0], Tws[1]), min(Tws[2], Tws[3]));

    // collect candidates <= T
    #pragma unroll
    for (int i = 0; i < 32; ++i) {
        if (ue[i] <= T) {
            unsigned pos = atomicAdd(&cntS, 1u);
            if (pos < KCAP) {
                cu[pos] = ue[i];
                cix[pos] = (unsigned short)(t * 32 + i);
            }
        }
    }
    __syncthreads();
    int C = (int)min(cntS, (unsigned)KCAP);
    // exact rank by (value, index): rank < 32 selected
    for (int cc = t; cc < C; cc += 256) {
        unsigned uc = cu[cc];
        unsigned short icd = cix[cc];
        int rank = 0;
        for (int j = 0; j < C; ++j) {
            unsigned uj = cu[j];
            rank += (uj < uc) || (uj == uc && cix[j] < icd);
        }
        if (rank < 32) knn_idx[g * 32 + rank] = (int)icd;
    }
}

// ---------------- fused per-group MLP (4 groups/block, 512 threads) ----------
__global__ __launch_bounds__(512) void mlp_kernel(
    const float* __restrict__ xyz, const int* __restrict__ cidx,
    const int* __restrict__ knn_idx,
    const float* __restrict__ w1, const float* __restrict__ b1,
    const float* __restrict__ sc1, const float* __restrict__ sh1,
    const short* __restrict__ w2fh, const short* __restrict__ w2fl,
    const float* __restrict__ b2,
    const float* __restrict__ sw1, const float* __restrict__ sb1,
    const short* __restrict__ Pfh, const short* __restrict__ Pfl,
    const float* __restrict__ bc3,
    const short* __restrict__ w3fh, const short* __restrict__ w3fl,
    const float* __restrict__ sc2, const float* __restrict__ sh2,
    const float* __restrict__ u, const float* __restrict__ ubp,
    short* __restrict__ yh)
{
    __shared__ __align__(16) char smem[74816];
    short* x1 = (short*)smem;                   // [128][128] bf16 swizzled
    short* x2 = (short*)smem;                   // [128][256] bf16 swizzled (overlays x1)
    // union region at 65536 (8KB): feat (P1-P2) | poolA (P5-P6) | fgpart (P6-P7)
    float* feat   = (float*)(smem + 65536);     // [128][12]... fits in 6KB < 8KB
    short* poolA  = (short*)(smem + 65536);     // [16][256] bf16 swizzled
    float* fgpart = (float*)(smem + 65536);     // [4][512] f32
    float* cen  = (float*)(smem + 73728);       // [4][3]
    float* scs  = (float*)(smem + 73792);       // [128]
    float* sms  = (float*)(smem + 74304);       // [128]

    int gb = blockIdx.x * 4;
    int bq = gb >> 9;
    int t = threadIdx.x;
    int lane = t & 63, wv = t >> 6, q = lane >> 4, r = lane & 15;
    const float* xb = xyz + (size_t)bq * 8192 * 3;

    // P0: centers + scs init
    if (t < 4) {
        int ci = cidx[gb + t];
        cen[t * 3 + 0] = xb[ci * 3 + 0];
        cen[t * 3 + 1] = xb[ci * 3 + 1];
        cen[t * 3 + 2] = xb[ci * 3 + 2];
    }
    if (t < 128) scs[t] = sb1[0];
    __syncthreads();

    // P1: feat gather (t<128 rows)
    if (t < 128) {
        int gg = t >> 5, kk = t & 31;
        int n = knn_idx[(gb + gg) * 32 + kk];
        float cxx = cen[gg * 3 + 0], cyy = cen[gg * 3 + 1], czz = cen[gg * 3 + 2];
        float nx = xb[n * 3 + 0], ny = xb[n * 3 + 1], nz = xb[n * 3 + 2];
        float rx = cxx - nx, ry = cyy - ny, rz = czz - nz;
        float rd = sqrtf(rx * rx + ry * ry + rz * rz);
        float* fr = feat + t * 12;
        fr[0] = rd; fr[1] = rx; fr[2] = ry; fr[3] = rz;
        fr[4] = cxx; fr[5] = cyy; fr[6] = czz;
        fr[7] = nx; fr[8] = ny; fr[9] = nz;
    }
    __syncthreads();

    // P2: conv1 + BN + ReLU -> x1 bf16 (swizzled)
    for (int i = 0; i < 32; ++i) {
        int flat = t + (i << 9);
        int row = flat >> 7, o = flat & 127;
        const float* wr = w1 + o * 10;
        const float* fr = feat + row * 12;
        float acc = b1[o];
        #pragma unroll
        for (int c = 0; c < 10; ++c) acc += fr[c] * wr[c];
        acc = fmaxf(acc * sc1[o] + sh1[o], 0.f);
        x1[row * 128 + (o ^ ((row & 7) << 3))] = f2bf(acc);
    }
    __syncthreads();

    // P3: conv2 via MFMA: M=128, N=256 (wave: 2 ct), K=128
    f32x4 acc2[8][2];
    #pragma unroll
    for (int rt = 0; rt < 8; ++rt)
        #pragma unroll
        for (int ctl = 0; ctl < 2; ++ctl) {
            float bv = b2[(wv * 2 + ctl) * 16 + r];
            acc2[rt][ctl] = (f32x4){bv, bv, bv, bv};
        }
    #pragma unroll
    for (int ks = 0; ks < 4; ++ks) {
        bf16x8 af[8];
        #pragma unroll
        for (int rt = 0; rt < 8; ++rt) {
            int row = rt * 16 + r;
            int kk = ks * 32 + q * 8;
            af[rt] = *(const bf16x8*)(x1 + row * 128 + (kk ^ ((row & 7) << 3)));
        }
        #pragma unroll
        for (int ctl = 0; ctl < 2; ++ctl) {
            int ct = wv * 2 + ctl;
            size_t woff = ((size_t)(ct * 4 + ks) * 64 + lane) * 8;
            bf16x8 bh = *(const bf16x8*)(w2fh + woff);
            bf16x8 bl = *(const bf16x8*)(w2fl + woff);
            #pragma unroll
            for (int rt = 0; rt < 8; ++rt) {
                acc2[rt][ctl] = MFMA16(af[rt], bl, acc2[rt][ctl]);
                acc2[rt][ctl] = MFMA16(af[rt], bh, acc2[rt][ctl]);
            }
        }
    }
    // attn1 score partials
    {
        float sw1v[2];
        #pragma unroll
        for (int ctl = 0; ctl < 2; ++ctl) sw1v[ctl] = sw1[(wv * 2 + ctl) * 16 + r];
        #pragma unroll
        for (int rt = 0; rt < 8; ++rt)
            #pragma unroll
            for (int j = 0; j < 4; ++j) {
                float s = sw1v[0] * acc2[rt][0][j] + sw1v[1] * acc2[rt][1][j];
                s += __shfl_xor(s, 1); s += __shfl_xor(s, 2);
                s += __shfl_xor(s, 4); s += __shfl_xor(s, 8);
                if (r == 0) atomicAdd(&scs[rt * 16 + q * 4 + j], s);
            }
    }
    __syncthreads();

    // P4: softmax1 + x2 store (bf16, swizzled; overlays x1 - dead)
    if (t < 128) {
        int gg = t >> 5;
        float mx = -INFINITY;
        for (int k = 0; k < 32; ++k) mx = fmaxf(mx, scs[gg * 32 + k]);
        float ssum = 0.f;
        for (int k = 0; k < 32; ++k) ssum += expf(scs[gg * 32 + k] - mx);
        sms[t] = expf(scs[t] - mx) / ssum;
    }
    #pragma unroll
    for (int rt = 0; rt < 8; ++rt)
        #pragma unroll
        for (int ctl = 0; ctl < 2; ++ctl) {
            int ch = (wv * 2 + ctl) * 16 + r;
            #pragma unroll
            for (int j = 0; j < 4; ++j) {
                int row = rt * 16 + q * 4 + j;
                x2[row * 256 + (ch ^ ((row & 7) << 3))] = f2bf(acc2[rt][ctl][j]);
            }
        }
    __syncthreads();

    // P5: pool1 -> poolA bf16 rows (hi: row=gg, lo: row=gg+4); zero rows 8-15;
    //     re-init scs for attn2
    {
        #pragma unroll
        for (int ctl = 0; ctl < 2; ++ctl)
            #pragma unroll
            for (int gg = 0; gg < 4; ++gg) {
                float p = 0.f;
                #pragma unroll
                for (int rr = 0; rr < 2; ++rr) {
                    int rt = gg * 2 + rr;
                    #pragma unroll
                    for (int j = 0; j < 4; ++j)
                        p += sms[rt * 16 + q * 4 + j] * acc2[rt][ctl][j];
                }
                p += __shfl_xor(p, 16);
                p += __shfl_xor(p, 32);
                if (q == 0) {
                    int ch = (wv * 2 + ctl) * 16 + r;
                    short h, l; bsplit(p, h, l);
                    poolA[gg * 256 + (ch ^ ((gg & 7) << 3))] = h;
                    poolA[(gg + 4) * 256 + (ch ^ (((gg + 4) & 7) << 3))] = l;
                }
            }
        // zero rows 8..15 (A rows beyond pool data)
        *(short*)(poolA + 2048 + t * 4 + 0) = 0;
        *(short*)(poolA + 2048 + t * 4 + 1) = 0;
        *(short*)(poolA + 2048 + t * 4 + 2) = 0;
        *(short*)(poolA + 2048 + t * 4 + 3) = 0;
        if (t < 128) scs[t] = ubp[0];
    }
    __syncthreads();

    // P6: fgpart via MFMA: A = poolA (rows: 0-3 pool_hi, 4-7 pool_lo),
    //     B = P frags (hi+lo), C-init bc3 on rows 0-3.
    {
        f32x4 accP[4];
        #pragma unroll
        for (int ctl = 0; ctl < 4; ++ctl) {
            float init = (q == 0) ? bc3[(wv * 4 + ctl) * 16 + r] : 0.f;
            accP[ctl] = (f32x4){init, init, init, init};
        }
        #pragma unroll
        for (int ks = 0; ks < 8; ++ks) {
            int kk = ks * 32 + q * 8;
            bf16x8 pa = *(const bf16x8*)(poolA + r * 256 + (kk ^ ((r & 7) << 3)));
            #pragma unroll
            for (int ctl = 0; ctl < 4; ++ctl) {
                size_t woff = ((size_t)((wv * 4 + ctl) * 8 + ks) * 64 + lane) * 8;
                bf16x8 ph = *(const bf16x8*)(Pfh + woff);
                bf16x8 pl = *(const bf16x8*)(Pfl + woff);
                accP[ctl] = MFMA16(pa, pl, accP[ctl]);
                accP[ctl] = MFMA16(pa, ph, accP[ctl]);
            }
        }
        __syncthreads();   // poolA reads complete before fgpart overwrite
        #pragma unroll
        for (int ctl = 0; ctl < 4; ++ctl)
            #pragma unroll
            for (int j = 0; j < 4; ++j) {
                float vsum = accP[ctl][j] + __shfl_xor(accP[ctl][j], 16);
                if (q == 0) fgpart[j * 512 + (wv * 4 + ctl) * 16 + r] = vsum;
            }
    }
    __syncthreads();

    // P7: conv3 via MFMA: M=128, N=512 (wave: 4 ct), K=256; C-init = fgpart
    f32x4 acc3[8][4];
    #pragma unroll
    for (int rt = 0; rt < 8; ++rt) {
        int gg = rt >> 1;
        #pragma unroll
        for (int ctl = 0; ctl < 4; ++ctl) {
            float fp = fgpart[gg * 512 + (wv * 4 + ctl) * 16 + r];
            acc3[rt][ctl] = (f32x4){fp, fp, fp, fp};
        }
    }
    #pragma unroll
    for (int ks = 0; ks < 8; ++ks) {
        bf16x8 af[8];
        #pragma unroll
        for (int rt = 0; rt < 8; ++rt) {
            int row = rt * 16 + r;
            int kk = ks * 32 + q * 8;
            af[rt] = *(const bf16x8*)(x2 + row * 256 + (kk ^ ((row & 7) << 3)));
        }
        #pragma unroll
        for (int ctl = 0; ctl < 4; ++ctl) {
            int ct = wv * 4 + ctl;
            size_t woff = ((size_t)(ct * 8 + ks) * 64 + lane) * 8;
            bf16x8 bh = *(const bf16x8*)(w3fh + woff);
            bf16x8 bl = *(const bf16x8*)(w3fl + woff);
            #pragma unroll
            for (int rt = 0; rt < 8; ++rt) {
                acc3[rt][ctl] = MFMA16(af[rt], bl, acc3[rt][ctl]);
                acc3[rt][ctl] = MFMA16(af[rt], bh, acc3[rt][ctl]);
            }
        }
    }
    // BN2 + ReLU in regs; attn2 score partials via u-collapse
    float uv[4];
    {
        #pragma unroll
        for (int ctl = 0; ctl < 4; ++ctl) {
            int ch = (wv * 4 + ctl) * 16 + r;
            float s = sc2[ch], sh = sh2[ch];
            uv[ctl] = u[ch];
            #pragma unroll
            for (int rt = 0; rt < 8; ++rt)
                #pragma unroll
                for (int j = 0; j < 4; ++j)
                    acc3[rt][ctl][j] = fmaxf(acc3[rt][ctl][j] * s + sh, 0.f);
        }
        #pragma unroll
        for (int rt = 0; rt < 8; ++rt)
            #pragma unroll
            for (int j = 0; j < 4; ++j) {
                float s = uv[0] * acc3[rt][0][j] + uv[1] * acc3[rt][1][j]
                        + uv[2] * acc3[rt][2][j] + uv[3] * acc3[rt][3][j];
                s += __shfl_xor(s, 1); s += __shfl_xor(s, 2);
                s += __shfl_xor(s, 4); s += __shfl_xor(s, 8);
                if (r == 0) atomicAdd(&scs[rt * 16 + q * 4 + j], s);
            }
    }
    __syncthreads();

    // P8: softmax2
    if (t < 128) {
        int gg = t >> 5;
        float mx = -INFINITY;
        for (int k = 0; k < 32; ++k) mx = fmaxf(mx, scs[gg * 32 + k]);
        float ssum = 0.f;
        for (int k = 0; k < 32; ++k) ssum += expf(scs[gg * 32 + k] - mx);
        sms[t] = expf(scs[t] - mx) / ssum;
    }
    __syncthreads();

    // P9: y[g][ch] = sum_k s[k]*x4[k][ch] -> global bf16
    {
        #pragma unroll
        for (int ctl = 0; ctl < 4; ++ctl)
            #pragma unroll
            for (int gg = 0; gg < 4; ++gg) {
                float p = 0.f;
                #pragma unroll
                for (int rr = 0; rr < 2; ++rr) {
                    int rt = gg * 2 + rr;
                    #pragma unroll
                    for (int j = 0; j < 4; ++j)
                        p += sms[rt * 16 + q * 4 + j] * acc3[rt][ctl][j];
                }
                p += __shfl_xor(p, 16);
                p += __shfl_xor(p, 32);
                if (q == 0) {
                    int grow = gb + gg;
                    int ch = (wv * 4 + ctl) * 16 + r;
                    yh[(size_t)grow * 512 + ch] = f2bf(p);
                }
            }
    }
}

// ---------------- fg2 GEMM: out = bb + y @ MT (M=4096,N=512,K=512) -----------
__global__ __launch_bounds__(256) void fg2_kernel(
    const short* __restrict__ yh,
    const short* __restrict__ MTfh, const short* __restrict__ MTfl,
    const float* __restrict__ bb, float* __restrict__ out_fg2)
{
    int gbase = blockIdx.x * 16;
    int t = threadIdx.x;
    int lane = t & 63, wv = t >> 6, q = lane >> 4, r = lane & 15;
    f32x4 acc[8];
    #pragma unroll
    for (int ctl = 0; ctl < 8; ++ctl) {
        float bv = bb[(wv * 8 + ctl) * 16 + r];
        acc[ctl] = (f32x4){bv, bv, bv, bv};
    }
    #pragma unroll
    for (int ks = 0; ks < 16; ++ks) {
        bf16x8 af = *(const bf16x8*)(yh + (size_t)(gbase + r) * 512 + ks * 32 + q * 8);
        #pragma unroll
        for (int ctl = 0; ctl < 8; ++ctl) {
            int ct = wv * 8 + ctl;
            size_t woff = ((size_t)(ct * 16 + ks) * 64 + lane) * 8;
            bf16x8 bh = *(const bf16x8*)(MTfh + woff);
            bf16x8 bl = *(const bf16x8*)(MTfl + woff);
            acc[ctl] = MFMA16(af, bl, acc[ctl]);
            acc[ctl] = MFMA16(af, bh, acc[ctl]);
        }
    }
    #pragma unroll
    for (int ctl = 0; ctl < 8; ++ctl) {
        int ch = (wv * 8 + ctl) * 16 + r;
        #pragma unroll
        for (int j = 0; j < 4; ++j) {
            int grow = gbase + q * 4 + j;
            out_fg2[(size_t)grow * 512 + ch] = acc[ctl][j];
        }
    }
}

extern "C" void kernel_launch(void* const* d_in, const int* in_sizes, int n_in,
                              void* d_out, int out_size, void* d_ws, size_t ws_size,
                              hipStream_t stream) {
    const float* xyz  = (const float*)d_in[0];
    const int*   cidx = (const int*)d_in[1];
    const float* w1   = (const float*)d_in[2];
    const float* b1   = (const float*)d_in[3];
    const float* g1   = (const float*)d_in[4];
    const float* be1  = (const float*)d_in[5];
    const float* m1   = (const float*)d_in[6];
    const float* v1   = (const float*)d_in[7];
    const float* w2   = (const float*)d_in[8];
    const float* b2   = (const float*)d_in[9];
    const float* sw1  = (const float*)d_in[10];
    const float* sb1  = (const float*)d_in[11];
    const float* mw1  = (const float*)d_in[12];
    const float* mb1  = (const float*)d_in[13];
    const float* w3   = (const float*)d_in[14];
    const float* b3   = (const float*)d_in[15];
    const float* g2   = (const float*)d_in[16];
    const float* be2  = (const float*)d_in[17];
    const float* m2   = (const float*)d_in[18];
    const float* v2   = (const float*)d_in[19];
    const float* w4   = (const float*)d_in[20];
    const float* b4   = (const float*)d_in[21];
    const float* sw2  = (const float*)d_in[22];
    const float* sb2  = (const float*)d_in[23];
    const float* mw2  = (const float*)d_in[24];
    const float* mb2  = (const float*)d_in[25];

    float* out = (float*)d_out;
    char* ws = (char*)d_ws;
    int*   knn_idx = (int*)(ws + 0);             // 524288
    short* w2fh = (short*)(ws + 524288);         // 65536
    short* w2fl = (short*)(ws + 589824);         // 65536
    short* w3fh = (short*)(ws + 655360);         // 262144
    short* w3fl = (short*)(ws + 917504);         // 262144
    short* Pfh  = (short*)(ws + 1179648);        // 262144
    short* Pfl  = (short*)(ws + 1441792);        // 262144
    float* bc3  = (float*)(ws + 1703936);        // 2048
    float* sc1  = (float*)(ws + 1705984);        // 512
    float* sh1  = (float*)(ws + 1706496);        // 512
    float* sc2  = (float*)(ws + 1707008);        // 2048
    float* sh2  = (float*)(ws + 1709056);        // 2048
    float* u    = (float*)(ws + 1711104);        // 2048
    float* bb   = (float*)(ws + 1713152);        // 2048
    float* ub   = (float*)(ws + 1715200);        // 256 (pad)
    short* MTfh = (short*)(ws + 1715456);        // 524288
    short* MTfl = (short*)(ws + 2239744);        // 524288
    short* yh   = (short*)(ws + 2764032);        // 4194304
    float* MTf  = (float*)(ws + 2764032);        // 1048576 (overlays yh; dead before yh written)

    prep_misc<<<256, 256, 0, stream>>>(g1, be1, m1, v1, w2, w3, b3,
                                       g2, be2, m2, v2, w4, sw2, b4, sb2, mw2, mb2, mb1,
                                       w2fh, w2fl, w3fh, w3fl,
                                       sc1, sh1, sc2, sh2, u, bb, ub, bc3);
    prep_P<<<256, 256, 0, stream>>>(mw1, w3, Pfh, Pfl);
    prep_MT<<<512, 256, 0, stream>>>(mw2, w4, MTf);
    prep_MTpack<<<512, 256, 0, stream>>>(MTf, MTfh, MTfl);
    knn_kernel<<<4096, 256, 0, stream>>>(xyz, cidx, knn_idx, out);
    mlp_kernel<<<1024, 512, 0, stream>>>(xyz, cidx, knn_idx,
                                         w1, b1, sc1, sh1, w2fh, w2fl, b2,
                                         sw1, sb1, Pfh, Pfl, bc3, w3fh, w3fl,
                                         sc2, sh2, u, ub, yh);
    fg2_kernel<<<256, 256, 0, stream>>>(yh, MTfh, MTfl, bb, out + 12288);
}

// Round 5
// 380.720 us; speedup vs baseline: 4.2931x; 1.1664x over previous
//
#include <hip/hip_runtime.h>
#include <math.h>

#define EPSV 1e-5f

typedef __attribute__((ext_vector_type(8))) short bf16x8;
typedef __attribute__((ext_vector_type(4))) float f32x4;

#define MFMA16(a, b, c) __builtin_amdgcn_mfma_f32_16x16x32_bf16(a, b, c, 0, 0, 0)

__device__ __forceinline__ short f2bf(float x) {
    unsigned u = __float_as_uint(x);
    unsigned r = (u + 0x7fffu + ((u >> 16) & 1u)) >> 16;
    return (short)r;
}
__device__ __forceinline__ float bf2f(short h) {
    return __uint_as_float(((unsigned)(unsigned short)h) << 16);
}
__device__ __forceinline__ void bsplit(float x, short& h, short& l) {
    h = f2bf(x);
    l = f2bf(x - bf2f(h));
}

// ============ fused prep + KNN: one launch, roles by blockIdx ================
// B < 4096            : KNN (g = B)
// B in [4096,4352)    : prep_P   (c = B-4096)
// B in [4352,4864)    : prep_MT + direct bf16 pack (qq = B-4352)
// B in [4864,4992)    : w2/w3 fragment packing (128 blocks, grid-strided)
// B in [4992,5056)    : bb  (8 q per block)
// B in [5056,5120)    : bc3 (8 o per block)
// B in [5120,5122)    : u   (256 c per block)
// B == 5122           : BN scale folds + ub
#define KCAP 2048
__global__ __launch_bounds__(256) void prep_knn(
    const float* __restrict__ xyz, const int* __restrict__ cidx,
    int* __restrict__ knn_idx, float* __restrict__ out_center,
    const float* __restrict__ w2, const float* __restrict__ w3,
    const float* __restrict__ mw1, const float* __restrict__ mw2,
    const float* __restrict__ w4, const float* __restrict__ b4,
    const float* __restrict__ sw2, const float* __restrict__ sb2,
    const float* __restrict__ mb2, const float* __restrict__ mb1,
    const float* __restrict__ b3,
    const float* __restrict__ g1, const float* __restrict__ be1,
    const float* __restrict__ m1, const float* __restrict__ v1,
    const float* __restrict__ g2, const float* __restrict__ be2,
    const float* __restrict__ m2, const float* __restrict__ v2,
    short* __restrict__ w2fh, short* __restrict__ w2fl,
    short* __restrict__ w3fh, short* __restrict__ w3fl,
    short* __restrict__ Pfh, short* __restrict__ Pfl,
    short* __restrict__ MTfh, short* __restrict__ MTfl,
    float* __restrict__ sc1, float* __restrict__ sh1,
    float* __restrict__ sc2, float* __restrict__ sh2,
    float* __restrict__ u, float* __restrict__ bb, float* __restrict__ ub,
    float* __restrict__ bc3)
{
    __shared__ __align__(16) char shm[12416];
    int B = blockIdx.x, t = threadIdx.x;
    int lane = t & 63, w = t >> 6;

    if (B < 4096) {
        // ---------------- KNN ----------------
        unsigned* cu = (unsigned*)shm;                       // 8192B
        unsigned short* cix = (unsigned short*)(shm + 8192); // 4096B
        unsigned* Tws = (unsigned*)(shm + 12288);            // 16B
        unsigned* cntS = (unsigned*)(shm + 12304);
        int g = B, b = g >> 9;
        const float* xb = xyz + (size_t)b * 8192 * 3;
        int ci = cidx[g];
        float cx = xb[ci * 3 + 0], cy = xb[ci * 3 + 1], cz = xb[ci * 3 + 2];
        float c2 = cx * cx + cy * cy + cz * cz;
        if (t < 3) out_center[g * 3 + t] = xb[ci * 3 + t];
        if (t == 0) *cntS = 0;

        const float4* p4 = (const float4*)xb + (size_t)t * 24;
        unsigned ue[32];
        unsigned vmin = 0xffffffffu;
        #pragma unroll
        for (int ii = 0; ii < 8; ++ii) {
            float4 v0 = p4[ii * 3 + 0];
            float4 v1 = p4[ii * 3 + 1];
            float4 v2 = p4[ii * 3 + 2];
            float px[4], py[4], pz[4];
            px[0] = v0.x; py[0] = v0.y; pz[0] = v0.z;
            px[1] = v0.w; py[1] = v1.x; pz[1] = v1.y;
            px[2] = v1.z; py[2] = v1.w; pz[2] = v2.x;
            px[3] = v2.y; py[3] = v2.z; pz[3] = v2.w;
            #pragma unroll
            for (int m = 0; m < 4; ++m) {
                float dx = px[m], dy = py[m], dz = pz[m];
                float n2 = dx * dx + dy * dy + dz * dz;
                float d = c2 + n2 - 2.f * (cx * dx + cy * dy + cz * dz);
                unsigned uu = __float_as_uint(d);
                uu = (uu & 0x80000000u) ? ~uu : (uu | 0x80000000u);
                ue[ii * 4 + m] = uu;
                vmin = min(vmin, uu);
            }
        }
        unsigned v = vmin;
        #pragma unroll
        for (int k = 2; k <= 64; k <<= 1) {
            #pragma unroll
            for (int jj = k >> 1; jj > 0; jj >>= 1) {
                unsigned o = __shfl_xor(v, jj);
                bool dir_asc = ((lane & k) == 0) || (k == 64);
                bool lower = (lane & jj) == 0;
                bool take_min = (lower == dir_asc);
                unsigned mn = min(v, o), mx = max(v, o);
                v = take_min ? mn : mx;
            }
        }
        unsigned Tw = __shfl(v, 31);
        if (lane == 0) Tws[w] = Tw;
        __syncthreads();
        unsigned T = min(min(Tws[0], Tws[1]), min(Tws[2], Tws[3]));
        #pragma unroll
        for (int i = 0; i < 32; ++i) {
            if (ue[i] <= T) {
                unsigned pos = atomicAdd(cntS, 1u);
                if (pos < KCAP) {
                    cu[pos] = ue[i];
                    cix[pos] = (unsigned short)(t * 32 + i);
                }
            }
        }
        __syncthreads();
        int C = (int)min(*cntS, (unsigned)KCAP);
        for (int cc = t; cc < C; cc += 256) {
            unsigned uc = cu[cc];
            unsigned short icd = cix[cc];
            int rank = 0;
            for (int j = 0; j < C; ++j) {
                unsigned uj = cu[j];
                rank += (uj < uc) || (uj == uc && cix[j] < icd);
            }
            if (rank < 32) knn_idx[g * 32 + rank] = (int)icd;
        }
        return;
    }

    if (B < 4352) {
        // ---------------- prep_P: P[c][o] = sum_d mw1[d][c]*w3[o][d] ----------
        float* col = (float*)shm;
        int c = B - 4096;
        col[t] = mw1[t * 256 + c];
        __syncthreads();
        int ks = c >> 5, qq = (c >> 3) & 3, jj = c & 7;
        for (int oo = t; oo < 512; oo += 256) {
            float acc = 0.f;
            for (int d = 0; d < 256; ++d) acc += col[d] * w3[oo * 512 + d];
            int ct = oo >> 4;
            size_t idx = ((size_t)(ct * 8 + ks) * 64 + qq * 16 + (oo & 15)) * 8 + jj;
            short h, l; bsplit(acc, h, l);
            Pfh[idx] = h; Pfl[idx] = l;
        }
        return;
    }

    if (B < 4864) {
        // ---------------- prep_MT + pack: MT[k][n]=sum_o mw2[n][o]w4[o][k] ----
        float* row = (float*)shm;
        int qq = B - 4352;
        row[t] = mw2[(size_t)qq * 512 + t];
        row[t + 256] = mw2[(size_t)qq * 512 + t + 256];
        __syncthreads();
        float a0 = 0.f, a1 = 0.f;
        for (int o = 0; o < 512; ++o) {
            float m = row[o];
            a0 += m * w4[o * 512 + t];
            a1 += m * w4[o * 512 + t + 256];
        }
        int ct = qq >> 4, nl = qq & 15;
        {
            int k = t;
            size_t i0 = (((size_t)(ct * 16 + (k >> 5))) << 9)
                      | ((((k >> 3) & 3) * 16 + nl) << 3) | (k & 7);
            short h, l; bsplit(a0, h, l);
            MTfh[i0] = h; MTfl[i0] = l;
        }
        {
            int k = t + 256;
            size_t i1 = (((size_t)(ct * 16 + (k >> 5))) << 9)
                      | ((((k >> 3) & 3) * 16 + nl) << 3) | (k & 7);
            short h, l; bsplit(a1, h, l);
            MTfh[i1] = h; MTfl[i1] = l;
        }
        return;
    }

    if (B < 4992) {
        // ---------------- w2/w3 fragment packing ------------------------------
        int tid = (B - 4864) * 256 + t;   // 0..32767
        {
            int i = tid;
            int j = i & 7, ln = (i >> 3) & 63, rest = i >> 9;
            int ks = rest & 3, ct = rest >> 2;
            int o = ct * 16 + (ln & 15);
            int k = ks * 32 + (ln >> 4) * 8 + j;
            short h, l; bsplit(w2[o * 128 + k], h, l);
            w2fh[i] = h; w2fl[i] = l;
        }
        #pragma unroll
        for (int s = 0; s < 4; ++s) {
            int i = tid + s * 32768;
            int j = i & 7, ln = (i >> 3) & 63, rest = i >> 9;
            int ks = rest & 7, ct = rest >> 3;
            int o = ct * 16 + (ln & 15);
            int c = 256 + ks * 32 + (ln >> 4) * 8 + j;
            short h, l; bsplit(w3[o * 512 + c], h, l);
            w3fh[i] = h; w3fl[i] = l;
        }
        return;
    }

    if (B < 5056) {
        // ---------------- bb: bb[q] = mb2[q] + sum_o mw2[q][o]*b4[o] ----------
        float* b4s = (float*)shm;            // 2048B
        float* red = (float*)(shm + 2048);   // 16B
        b4s[t] = b4[t];
        b4s[t + 256] = b4[t + 256];
        __syncthreads();
        int q0 = (B - 4992) * 8;
        for (int i = 0; i < 8; ++i) {
            int q = q0 + i;
            float part = mw2[(size_t)q * 512 + t] * b4s[t]
                       + mw2[(size_t)q * 512 + 256 + t] * b4s[256 + t];
            #pragma unroll
            for (int off = 32; off > 0; off >>= 1) part += __shfl_down(part, off);
            if (lane == 0) red[w] = part;
            __syncthreads();
            if (t == 0) bb[q] = mb2[q] + red[0] + red[1] + red[2] + red[3];
            __syncthreads();
        }
        return;
    }

    if (B < 5120) {
        // ---------------- bc3[o] = b3[o] + sum_d mb1[d]*w3[o][d], d<256 -------
        float* mb1s = (float*)shm;           // 1024B
        float* red = (float*)(shm + 1024);
        mb1s[t] = mb1[t];
        __syncthreads();
        int o0 = (B - 5056) * 8;
        for (int i = 0; i < 8; ++i) {
            int o = o0 + i;
            float part = w3[(size_t)o * 512 + t] * mb1s[t];
            #pragma unroll
            for (int off = 32; off > 0; off >>= 1) part += __shfl_down(part, off);
            if (lane == 0) red[w] = part;
            __syncthreads();
            if (t == 0) bc3[o] = b3[o] + red[0] + red[1] + red[2] + red[3];
            __syncthreads();
        }
        return;
    }

    if (B < 5122) {
        // ---------------- u[c] = sum_o sw2[o]*w4[o][c] ------------------------
        int c = (B - 5120) * 256 + t;
        float acc = 0.f;
        for (int o = 0; o < 512; ++o) acc += sw2[o] * w4[o * 512 + c];
        u[c] = acc;
        return;
    }

    // -------------------- scales + ub ----------------------------------------
    if (t < 128) {
        float s = g1[t] * rsqrtf(v1[t] + EPSV);
        sc1[t] = s; sh1[t] = be1[t] - m1[t] * s;
    }
    {
        float s = g2[t] * rsqrtf(v2[t] + EPSV);
        sc2[t] = s; sh2[t] = be2[t] - m2[t] * s;
        s = g2[t + 256] * rsqrtf(v2[t + 256] + EPSV);
        sc2[t + 256] = s; sh2[t + 256] = be2[t + 256] - m2[t + 256] * s;
    }
    if (t < 64) {
        float part = 0.f;
        #pragma unroll
        for (int i = 0; i < 8; ++i) part += sw2[t * 8 + i] * b4[t * 8 + i];
        #pragma unroll
        for (int off = 32; off > 0; off >>= 1) part += __shfl_down(part, off);
        if (t == 0) ub[0] = sb2[0] + part;
    }
}

// ---------------- fused per-group MLP (4 groups/block, 512 threads) ----------
__global__ __launch_bounds__(512) void mlp_kernel(
    const float* __restrict__ xyz, const int* __restrict__ cidx,
    const int* __restrict__ knn_idx,
    const float* __restrict__ w1, const float* __restrict__ b1,
    const float* __restrict__ sc1, const float* __restrict__ sh1,
    const short* __restrict__ w2fh, const short* __restrict__ w2fl,
    const float* __restrict__ b2,
    const float* __restrict__ sw1, const float* __restrict__ sb1,
    const short* __restrict__ Pfh, const short* __restrict__ Pfl,
    const float* __restrict__ bc3,
    const short* __restrict__ w3fh, const short* __restrict__ w3fl,
    const float* __restrict__ sc2, const float* __restrict__ sh2,
    const float* __restrict__ u, const float* __restrict__ ubp,
    short* __restrict__ yh)
{
    __shared__ __align__(16) char smem[74816];
    short* x1 = (short*)smem;                   // [128][128] bf16 swizzled
    short* x2 = (short*)smem;                   // [128][256] bf16 swizzled (overlays x1)
    // union region at 65536 (8KB): feat (P1-P2) | poolA (P5-P6) | fgpart (P6-P7)
    float* feat   = (float*)(smem + 65536);     // [128][13] padded stride (6656B)
    short* poolA  = (short*)(smem + 65536);     // [16][256] bf16 swizzled
    float* fgpart = (float*)(smem + 65536);     // [4][512] f32
    float* cen  = (float*)(smem + 73728);       // [4][3]
    float* scs  = (float*)(smem + 73792);       // [128]
    float* sms  = (float*)(smem + 74304);       // [128]

    int gb = blockIdx.x * 4;
    int bq = gb >> 9;
    int t = threadIdx.x;
    int lane = t & 63, wv = t >> 6, q = lane >> 4, r = lane & 15;
    const float* xb = xyz + (size_t)bq * 8192 * 3;

    // P0: centers + scs init
    if (t < 4) {
        int ci = cidx[gb + t];
        cen[t * 3 + 0] = xb[ci * 3 + 0];
        cen[t * 3 + 1] = xb[ci * 3 + 1];
        cen[t * 3 + 2] = xb[ci * 3 + 2];
    }
    if (t < 128) scs[t] = sb1[0];
    __syncthreads();

    // P1: feat gather (t<128 rows), stride 13 (bank-conflict-free)
    if (t < 128) {
        int gg = t >> 5, kk = t & 31;
        int n = knn_idx[(gb + gg) * 32 + kk];
        float cxx = cen[gg * 3 + 0], cyy = cen[gg * 3 + 1], czz = cen[gg * 3 + 2];
        float nx = xb[n * 3 + 0], ny = xb[n * 3 + 1], nz = xb[n * 3 + 2];
        float rx = cxx - nx, ry = cyy - ny, rz = czz - nz;
        float rd = sqrtf(rx * rx + ry * ry + rz * rz);
        float* fr = feat + t * 13;
        fr[0] = rd; fr[1] = rx; fr[2] = ry; fr[3] = rz;
        fr[4] = cxx; fr[5] = cyy; fr[6] = czz;
        fr[7] = nx; fr[8] = ny; fr[9] = nz;
    }
    __syncthreads();

    // P2: conv1 + BN + ReLU -> x1 bf16 (swizzled)
    for (int i = 0; i < 32; ++i) {
        int flat = t + (i << 9);
        int row = flat >> 7, o = flat & 127;
        const float* wr = w1 + o * 10;
        const float* fr = feat + row * 13;
        float acc = b1[o];
        #pragma unroll
        for (int c = 0; c < 10; ++c) acc += fr[c] * wr[c];
        acc = fmaxf(acc * sc1[o] + sh1[o], 0.f);
        x1[row * 128 + (o ^ ((row & 7) << 3))] = f2bf(acc);
    }
    __syncthreads();

    // P3: conv2 via MFMA: M=128, N=256 (wave: 2 ct), K=128
    f32x4 acc2[8][2];
    #pragma unroll
    for (int rt = 0; rt < 8; ++rt)
        #pragma unroll
        for (int ctl = 0; ctl < 2; ++ctl) {
            float bv = b2[(wv * 2 + ctl) * 16 + r];
            acc2[rt][ctl] = (f32x4){bv, bv, bv, bv};
        }
    #pragma unroll
    for (int ks = 0; ks < 4; ++ks) {
        bf16x8 af[8];
        #pragma unroll
        for (int rt = 0; rt < 8; ++rt) {
            int row = rt * 16 + r;
            int kk = ks * 32 + q * 8;
            af[rt] = *(const bf16x8*)(x1 + row * 128 + (kk ^ ((row & 7) << 3)));
        }
        #pragma unroll
        for (int ctl = 0; ctl < 2; ++ctl) {
            int ct = wv * 2 + ctl;
            size_t woff = ((size_t)(ct * 4 + ks) * 64 + lane) * 8;
            bf16x8 bh = *(const bf16x8*)(w2fh + woff);
            bf16x8 bl = *(const bf16x8*)(w2fl + woff);
            #pragma unroll
            for (int rt = 0; rt < 8; ++rt) {
                acc2[rt][ctl] = MFMA16(af[rt], bl, acc2[rt][ctl]);
                acc2[rt][ctl] = MFMA16(af[rt], bh, acc2[rt][ctl]);
            }
        }
    }
    // attn1 score partials
    {
        float sw1v[2];
        #pragma unroll
        for (int ctl = 0; ctl < 2; ++ctl) sw1v[ctl] = sw1[(wv * 2 + ctl) * 16 + r];
        #pragma unroll
        for (int rt = 0; rt < 8; ++rt)
            #pragma unroll
            for (int j = 0; j < 4; ++j) {
                float s = sw1v[0] * acc2[rt][0][j] + sw1v[1] * acc2[rt][1][j];
                s += __shfl_xor(s, 1); s += __shfl_xor(s, 2);
                s += __shfl_xor(s, 4); s += __shfl_xor(s, 8);
                if (r == 0) atomicAdd(&scs[rt * 16 + q * 4 + j], s);
            }
    }
    __syncthreads();

    // P4: softmax1 + x2 store (bf16, swizzled; overlays x1 - dead)
    if (t < 128) {
        int gg = t >> 5;
        float mx = -INFINITY;
        for (int k = 0; k < 32; ++k) mx = fmaxf(mx, scs[gg * 32 + k]);
        float ssum = 0.f;
        for (int k = 0; k < 32; ++k) ssum += expf(scs[gg * 32 + k] - mx);
        sms[t] = expf(scs[t] - mx) / ssum;
    }
    #pragma unroll
    for (int rt = 0; rt < 8; ++rt)
        #pragma unroll
        for (int ctl = 0; ctl < 2; ++ctl) {
            int ch = (wv * 2 + ctl) * 16 + r;
            #pragma unroll
            for (int j = 0; j < 4; ++j) {
                int row = rt * 16 + q * 4 + j;
                x2[row * 256 + (ch ^ ((row & 7) << 3))] = f2bf(acc2[rt][ctl][j]);
            }
        }
    __syncthreads();

    // P5: pool1 -> poolA bf16 rows (hi: row=gg, lo: row=gg+4); zero rows 8-15
    {
        #pragma unroll
        for (int ctl = 0; ctl < 2; ++ctl)
            #pragma unroll
            for (int gg = 0; gg < 4; ++gg) {
                float p = 0.f;
                #pragma unroll
                for (int rr = 0; rr < 2; ++rr) {
                    int rt = gg * 2 + rr;
                    #pragma unroll
                    for (int j = 0; j < 4; ++j)
                        p += sms[rt * 16 + q * 4 + j] * acc2[rt][ctl][j];
                }
                p += __shfl_xor(p, 16);
                p += __shfl_xor(p, 32);
                if (q == 0) {
                    int ch = (wv * 2 + ctl) * 16 + r;
                    short h, l; bsplit(p, h, l);
                    poolA[gg * 256 + (ch ^ ((gg & 7) << 3))] = h;
                    poolA[(gg + 4) * 256 + (ch ^ (((gg + 4) & 7) << 3))] = l;
                }
            }
        *(short*)(poolA + 2048 + t * 4 + 0) = 0;
        *(short*)(poolA + 2048 + t * 4 + 1) = 0;
        *(short*)(poolA + 2048 + t * 4 + 2) = 0;
        *(short*)(poolA + 2048 + t * 4 + 3) = 0;
        if (t < 128) scs[t] = ubp[0];
    }
    __syncthreads();

    // P6: fgpart via MFMA
    {
        f32x4 accP[4];
        #pragma unroll
        for (int ctl = 0; ctl < 4; ++ctl) {
            float init = (q == 0) ? bc3[(wv * 4 + ctl) * 16 + r] : 0.f;
            accP[ctl] = (f32x4){init, init, init, init};
        }
        #pragma unroll
        for (int ks = 0; ks < 8; ++ks) {
            int kk = ks * 32 + q * 8;
            bf16x8 pa = *(const bf16x8*)(poolA + r * 256 + (kk ^ ((r & 7) << 3)));
            #pragma unroll
            for (int ctl = 0; ctl < 4; ++ctl) {
                size_t woff = ((size_t)((wv * 4 + ctl) * 8 + ks) * 64 + lane) * 8;
                bf16x8 ph = *(const bf16x8*)(Pfh + woff);
                bf16x8 pl = *(const bf16x8*)(Pfl + woff);
                accP[ctl] = MFMA16(pa, pl, accP[ctl]);
                accP[ctl] = MFMA16(pa, ph, accP[ctl]);
            }
        }
        __syncthreads();
        #pragma unroll
        for (int ctl = 0; ctl < 4; ++ctl)
            #pragma unroll
            for (int j = 0; j < 4; ++j) {
                float vsum = accP[ctl][j] + __shfl_xor(accP[ctl][j], 16);
                if (q == 0) fgpart[j * 512 + (wv * 4 + ctl) * 16 + r] = vsum;
            }
    }
    __syncthreads();

    // P7: conv3 via MFMA: M=128, N=512 (wave: 4 ct), K=256; C-init = fgpart
    f32x4 acc3[8][4];
    #pragma unroll
    for (int rt = 0; rt < 8; ++rt) {
        int gg = rt >> 1;
        #pragma unroll
        for (int ctl = 0; ctl < 4; ++ctl) {
            float fp = fgpart[gg * 512 + (wv * 4 + ctl) * 16 + r];
            acc3[rt][ctl] = (f32x4){fp, fp, fp, fp};
        }
    }
    #pragma unroll
    for (int ks = 0; ks < 8; ++ks) {
        bf16x8 af[8];
        #pragma unroll
        for (int rt = 0; rt < 8; ++rt) {
            int row = rt * 16 + r;
            int kk = ks * 32 + q * 8;
            af[rt] = *(const bf16x8*)(x2 + row * 256 + (kk ^ ((row & 7) << 3)));
        }
        #pragma unroll
        for (int ctl = 0; ctl < 4; ++ctl) {
            int ct = wv * 4 + ctl;
            size_t woff = ((size_t)(ct * 8 + ks) * 64 + lane) * 8;
            bf16x8 bh = *(const bf16x8*)(w3fh + woff);
            bf16x8 bl = *(const bf16x8*)(w3fl + woff);
            #pragma unroll
            for (int rt = 0; rt < 8; ++rt) {
                acc3[rt][ctl] = MFMA16(af[rt], bl, acc3[rt][ctl]);
                acc3[rt][ctl] = MFMA16(af[rt], bh, acc3[rt][ctl]);
            }
        }
    }
    // BN2 + ReLU in regs; attn2 score partials via u-collapse
    float uv[4];
    {
        #pragma unroll
        for (int ctl = 0; ctl < 4; ++ctl) {
            int ch = (wv * 4 + ctl) * 16 + r;
            float s = sc2[ch], sh = sh2[ch];
            uv[ctl] = u[ch];
            #pragma unroll
            for (int rt = 0; rt < 8; ++rt)
                #pragma unroll
                for (int j = 0; j < 4; ++j)
                    acc3[rt][ctl][j] = fmaxf(acc3[rt][ctl][j] * s + sh, 0.f);
        }
        #pragma unroll
        for (int rt = 0; rt < 8; ++rt)
            #pragma unroll
            for (int j = 0; j < 4; ++j) {
                float s = uv[0] * acc3[rt][0][j] + uv[1] * acc3[rt][1][j]
                        + uv[2] * acc3[rt][2][j] + uv[3] * acc3[rt][3][j];
                s += __shfl_xor(s, 1); s += __shfl_xor(s, 2);
                s += __shfl_xor(s, 4); s += __shfl_xor(s, 8);
                if (r == 0) atomicAdd(&scs[rt * 16 + q * 4 + j], s);
            }
    }
    __syncthreads();

    // P8: softmax2
    if (t < 128) {
        int gg = t >> 5;
        float mx = -INFINITY;
        for (int k = 0; k < 32; ++k) mx = fmaxf(mx, scs[gg * 32 + k]);
        float ssum = 0.f;
        for (int k = 0; k < 32; ++k) ssum += expf(scs[gg * 32 + k] - mx);
        sms[t] = expf(scs[t] - mx) / ssum;
    }
    __syncthreads();

    // P9: y[g][ch] = sum_k s[k]*x4[k][ch] -> global bf16
    {
        #pragma unroll
        for (int ctl = 0; ctl < 4; ++ctl)
            #pragma unroll
            for (int gg = 0; gg < 4; ++gg) {
                float p = 0.f;
                #pragma unroll
                for (int rr = 0; rr < 2; ++rr) {
                    int rt = gg * 2 + rr;
                    #pragma unroll
                    for (int j = 0; j < 4; ++j)
                        p += sms[rt * 16 + q * 4 + j] * acc3[rt][ctl][j];
                }
                p += __shfl_xor(p, 16);
                p += __shfl_xor(p, 32);
                if (q == 0) {
                    int grow = gb + gg;
                    int ch = (wv * 4 + ctl) * 16 + r;
                    yh[(size_t)grow * 512 + ch] = f2bf(p);
                }
            }
    }
}

// ---------------- fg2 GEMM: out = bb + y @ MT (M=4096,N=512,K=512) -----------
__global__ __launch_bounds__(256) void fg2_kernel(
    const short* __restrict__ yh,
    const short* __restrict__ MTfh, const short* __restrict__ MTfl,
    const float* __restrict__ bb, float* __restrict__ out_fg2)
{
    int gbase = blockIdx.x * 16;
    int t = threadIdx.x;
    int lane = t & 63, wv = t >> 6, q = lane >> 4, r = lane & 15;
    f32x4 acc[8];
    #pragma unroll
    for (int ctl = 0; ctl < 8; ++ctl) {
        float bv = bb[(wv * 8 + ctl) * 16 + r];
        acc[ctl] = (f32x4){bv, bv, bv, bv};
    }
    #pragma unroll
    for (int ks = 0; ks < 16; ++ks) {
        bf16x8 af = *(const bf16x8*)(yh + (size_t)(gbase + r) * 512 + ks * 32 + q * 8);
        #pragma unroll
        for (int ctl = 0; ctl < 8; ++ctl) {
            int ct = wv * 8 + ctl;
            size_t woff = ((size_t)(ct * 16 + ks) * 64 + lane) * 8;
            bf16x8 bh = *(const bf16x8*)(MTfh + woff);
            bf16x8 bl = *(const bf16x8*)(MTfl + woff);
            acc[ctl] = MFMA16(af, bl, acc[ctl]);
            acc[ctl] = MFMA16(af, bh, acc[ctl]);
        }
    }
    #pragma unroll
    for (int ctl = 0; ctl < 8; ++ctl) {
        int ch = (wv * 8 + ctl) * 16 + r;
        #pragma unroll
        for (int j = 0; j < 4; ++j) {
            int grow = gbase + q * 4 + j;
            out_fg2[(size_t)grow * 512 + ch] = acc[ctl][j];
        }
    }
}

extern "C" void kernel_launch(void* const* d_in, const int* in_sizes, int n_in,
                              void* d_out, int out_size, void* d_ws, size_t ws_size,
                              hipStream_t stream) {
    const float* xyz  = (const float*)d_in[0];
    const int*   cidx = (const int*)d_in[1];
    const float* w1   = (const float*)d_in[2];
    const float* b1   = (const float*)d_in[3];
    const float* g1   = (const float*)d_in[4];
    const float* be1  = (const float*)d_in[5];
    const float* m1   = (const float*)d_in[6];
    const float* v1   = (const float*)d_in[7];
    const float* w2   = (const float*)d_in[8];
    const float* b2   = (const float*)d_in[9];
    const float* sw1  = (const float*)d_in[10];
    const float* sb1  = (const float*)d_in[11];
    const float* mw1  = (const float*)d_in[12];
    const float* mb1  = (const float*)d_in[13];
    const float* w3   = (const float*)d_in[14];
    const float* b3   = (const float*)d_in[15];
    const float* g2   = (const float*)d_in[16];
    const float* be2  = (const float*)d_in[17];
    const float* m2   = (const float*)d_in[18];
    const float* v2   = (const float*)d_in[19];
    const float* w4   = (const float*)d_in[20];
    const float* b4   = (const float*)d_in[21];
    const float* sw2  = (const float*)d_in[22];
    const float* sb2  = (const float*)d_in[23];
    const float* mw2  = (const float*)d_in[24];
    const float* mb2  = (const float*)d_in[25];

    float* out = (float*)d_out;
    char* ws = (char*)d_ws;
    int*   knn_idx = (int*)(ws + 0);             // 524288
    short* w2fh = (short*)(ws + 524288);         // 65536
    short* w2fl = (short*)(ws + 589824);         // 65536
    short* w3fh = (short*)(ws + 655360);         // 262144
    short* w3fl = (short*)(ws + 917504);         // 262144
    short* Pfh  = (short*)(ws + 1179648);        // 262144
    short* Pfl  = (short*)(ws + 1441792);        // 262144
    float* bc3  = (float*)(ws + 1703936);        // 2048
    float* sc1  = (float*)(ws + 1705984);        // 512
    float* sh1  = (float*)(ws + 1706496);        // 512
    float* sc2  = (float*)(ws + 1707008);        // 2048
    float* sh2  = (float*)(ws + 1709056);        // 2048
    float* u    = (float*)(ws + 1711104);        // 2048
    float* bb   = (float*)(ws + 1713152);        // 2048
    float* ub   = (float*)(ws + 1715200);        // 256 (pad)
    short* MTfh = (short*)(ws + 1715456);        // 524288
    short* MTfl = (short*)(ws + 2239744);        // 524288
    short* yh   = (short*)(ws + 2764032);        // 4194304

    prep_knn<<<5123, 256, 0, stream>>>(xyz, cidx, knn_idx, out,
                                       w2, w3, mw1, mw2, w4, b4, sw2, sb2, mb2, mb1, b3,
                                       g1, be1, m1, v1, g2, be2, m2, v2,
                                       w2fh, w2fl, w3fh, w3fl, Pfh, Pfl, MTfh, MTfl,
                                       sc1, sh1, sc2, sh2, u, bb, ub, bc3);
    mlp_kernel<<<1024, 512, 0, stream>>>(xyz, cidx, knn_idx,
                                         w1, b1, sc1, sh1, w2fh, w2fl, b2,
                                         sw1, sb1, Pfh, Pfl, bc3, w3fh, w3fl,
                                         sc2, sh2, u, ub, yh);
    fg2_kernel<<<256, 256, 0, stream>>>(yh, MTfh, MTfl, bb, out + 12288);
}

// Round 6
// 365.353 us; speedup vs baseline: 4.4737x; 1.0421x over previous
//
#include <hip/hip_runtime.h>
#include <math.h>

#define EPSV 1e-5f

typedef __attribute__((ext_vector_type(8))) short bf16x8;
typedef __attribute__((ext_vector_type(4))) float f32x4;

#define MFMA16(a, b, c) __builtin_amdgcn_mfma_f32_16x16x32_bf16(a, b, c, 0, 0, 0)

__device__ __forceinline__ short f2bf(float x) {
    unsigned u = __float_as_uint(x);
    unsigned r = (u + 0x7fffu + ((u >> 16) & 1u)) >> 16;
    return (short)r;
}
__device__ __forceinline__ float bf2f(short h) {
    return __uint_as_float(((unsigned)(unsigned short)h) << 16);
}
__device__ __forceinline__ void bsplit(float x, short& h, short& l) {
    h = f2bf(x);
    l = f2bf(x - bf2f(h));
}

// ============ fused prep + KNN: one launch, roles by blockIdx ================
#define KCAP 2048
__global__ __launch_bounds__(256) void prep_knn(
    const float* __restrict__ xyz, const int* __restrict__ cidx,
    int* __restrict__ knn_idx, float* __restrict__ out_center,
    const float* __restrict__ w2, const float* __restrict__ w3,
    const float* __restrict__ mw1, const float* __restrict__ mw2,
    const float* __restrict__ w4, const float* __restrict__ b4,
    const float* __restrict__ sw2, const float* __restrict__ sb2,
    const float* __restrict__ mb2, const float* __restrict__ mb1,
    const float* __restrict__ b3,
    const float* __restrict__ g1, const float* __restrict__ be1,
    const float* __restrict__ m1, const float* __restrict__ v1,
    const float* __restrict__ g2, const float* __restrict__ be2,
    const float* __restrict__ m2, const float* __restrict__ v2,
    short* __restrict__ w2fh, short* __restrict__ w3fh,
    short* __restrict__ Pfh, short* __restrict__ Pfl,
    short* __restrict__ MTfh, short* __restrict__ MTfl,
    float* __restrict__ sc1, float* __restrict__ sh1,
    float* __restrict__ sc2, float* __restrict__ sh2,
    float* __restrict__ u, float* __restrict__ bb, float* __restrict__ ub,
    float* __restrict__ bc3)
{
    __shared__ __align__(16) char shm[12416];
    int B = blockIdx.x, t = threadIdx.x;
    int lane = t & 63, w = t >> 6;

    if (B < 4096) {
        // ---------------- KNN ----------------
        unsigned* cu = (unsigned*)shm;                       // 8192B
        unsigned short* cix = (unsigned short*)(shm + 8192); // 4096B
        unsigned* Tws = (unsigned*)(shm + 12288);            // 16B
        unsigned* cntS = (unsigned*)(shm + 12304);
        int g = B, b = g >> 9;
        const float* xb = xyz + (size_t)b * 8192 * 3;
        int ci = cidx[g];
        float cx = xb[ci * 3 + 0], cy = xb[ci * 3 + 1], cz = xb[ci * 3 + 2];
        float c2 = cx * cx + cy * cy + cz * cz;
        if (t < 3) out_center[g * 3 + t] = xb[ci * 3 + t];
        if (t == 0) *cntS = 0;

        const float4* p4 = (const float4*)xb + (size_t)t * 24;
        unsigned ue[32];
        unsigned vmin = 0xffffffffu;
        #pragma unroll
        for (int ii = 0; ii < 8; ++ii) {
            float4 v0 = p4[ii * 3 + 0];
            float4 v1 = p4[ii * 3 + 1];
            float4 v2 = p4[ii * 3 + 2];
            float px[4], py[4], pz[4];
            px[0] = v0.x; py[0] = v0.y; pz[0] = v0.z;
            px[1] = v0.w; py[1] = v1.x; pz[1] = v1.y;
            px[2] = v1.z; py[2] = v1.w; pz[2] = v2.x;
            px[3] = v2.y; py[3] = v2.z; pz[3] = v2.w;
            #pragma unroll
            for (int m = 0; m < 4; ++m) {
                float dx = px[m], dy = py[m], dz = pz[m];
                float n2 = dx * dx + dy * dy + dz * dz;
                float d = c2 + n2 - 2.f * (cx * dx + cy * dy + cz * dz);
                unsigned uu = __float_as_uint(d);
                uu = (uu & 0x80000000u) ? ~uu : (uu | 0x80000000u);
                ue[ii * 4 + m] = uu;
                vmin = min(vmin, uu);
            }
        }
        unsigned v = vmin;
        #pragma unroll
        for (int k = 2; k <= 64; k <<= 1) {
            #pragma unroll
            for (int jj = k >> 1; jj > 0; jj >>= 1) {
                unsigned o = __shfl_xor(v, jj);
                bool dir_asc = ((lane & k) == 0) || (k == 64);
                bool lower = (lane & jj) == 0;
                bool take_min = (lower == dir_asc);
                unsigned mn = min(v, o), mx = max(v, o);
                v = take_min ? mn : mx;
            }
        }
        unsigned Tw = __shfl(v, 31);
        if (lane == 0) Tws[w] = Tw;
        __syncthreads();
        unsigned T = min(min(Tws[0], Tws[1]), min(Tws[2], Tws[3]));
        #pragma unroll
        for (int i = 0; i < 32; ++i) {
            if (ue[i] <= T) {
                unsigned pos = atomicAdd(cntS, 1u);
                if (pos < KCAP) {
                    cu[pos] = ue[i];
                    cix[pos] = (unsigned short)(t * 32 + i);
                }
            }
        }
        __syncthreads();
        int C = (int)min(*cntS, (unsigned)KCAP);
        for (int cc = t; cc < C; cc += 256) {
            unsigned uc = cu[cc];
            unsigned short icd = cix[cc];
            int rank = 0;
            for (int j = 0; j < C; ++j) {
                unsigned uj = cu[j];
                rank += (uj < uc) || (uj == uc && cix[j] < icd);
            }
            if (rank < 32) knn_idx[g * 32 + rank] = (int)icd;
        }
        return;
    }

    if (B < 4352) {
        // prep_P: P[c][o] = sum_d mw1[d][c]*w3[o][d]  (hi+lo kept)
        float* col = (float*)shm;
        int c = B - 4096;
        col[t] = mw1[t * 256 + c];
        __syncthreads();
        int ks = c >> 5, qq = (c >> 3) & 3, jj = c & 7;
        for (int oo = t; oo < 512; oo += 256) {
            float acc = 0.f;
            for (int d = 0; d < 256; ++d) acc += col[d] * w3[oo * 512 + d];
            int ct = oo >> 4;
            size_t idx = ((size_t)(ct * 8 + ks) * 64 + qq * 16 + (oo & 15)) * 8 + jj;
            short h, l; bsplit(acc, h, l);
            Pfh[idx] = h; Pfl[idx] = l;
        }
        return;
    }

    if (B < 4864) {
        // prep_MT + pack (hi+lo kept)
        float* row = (float*)shm;
        int qq = B - 4352;
        row[t] = mw2[(size_t)qq * 512 + t];
        row[t + 256] = mw2[(size_t)qq * 512 + t + 256];
        __syncthreads();
        float a0 = 0.f, a1 = 0.f;
        for (int o = 0; o < 512; ++o) {
            float m = row[o];
            a0 += m * w4[o * 512 + t];
            a1 += m * w4[o * 512 + t + 256];
        }
        int ct = qq >> 4, nl = qq & 15;
        {
            int k = t;
            size_t i0 = (((size_t)(ct * 16 + (k >> 5))) << 9)
                      | ((((k >> 3) & 3) * 16 + nl) << 3) | (k & 7);
            short h, l; bsplit(a0, h, l);
            MTfh[i0] = h; MTfl[i0] = l;
        }
        {
            int k = t + 256;
            size_t i1 = (((size_t)(ct * 16 + (k >> 5))) << 9)
                      | ((((k >> 3) & 3) * 16 + nl) << 3) | (k & 7);
            short h, l; bsplit(a1, h, l);
            MTfh[i1] = h; MTfl[i1] = l;
        }
        return;
    }

    if (B < 4992) {
        // w2/w3 fragment packing (hi only)
        int tid = (B - 4864) * 256 + t;
        {
            int i = tid;
            int j = i & 7, ln = (i >> 3) & 63, rest = i >> 9;
            int ks = rest & 3, ct = rest >> 2;
            int o = ct * 16 + (ln & 15);
            int k = ks * 32 + (ln >> 4) * 8 + j;
            w2fh[i] = f2bf(w2[o * 128 + k]);
        }
        #pragma unroll
        for (int s = 0; s < 4; ++s) {
            int i = tid + s * 32768;
            int j = i & 7, ln = (i >> 3) & 63, rest = i >> 9;
            int ks = rest & 7, ct = rest >> 3;
            int o = ct * 16 + (ln & 15);
            int c = 256 + ks * 32 + (ln >> 4) * 8 + j;
            w3fh[i] = f2bf(w3[o * 512 + c]);
        }
        return;
    }

    if (B < 5056) {
        float* b4s = (float*)shm;
        float* red = (float*)(shm + 2048);
        b4s[t] = b4[t];
        b4s[t + 256] = b4[t + 256];
        __syncthreads();
        int q0 = (B - 4992) * 8;
        for (int i = 0; i < 8; ++i) {
            int q = q0 + i;
            float part = mw2[(size_t)q * 512 + t] * b4s[t]
                       + mw2[(size_t)q * 512 + 256 + t] * b4s[256 + t];
            #pragma unroll
            for (int off = 32; off > 0; off >>= 1) part += __shfl_down(part, off);
            if (lane == 0) red[w] = part;
            __syncthreads();
            if (t == 0) bb[q] = mb2[q] + red[0] + red[1] + red[2] + red[3];
            __syncthreads();
        }
        return;
    }

    if (B < 5120) {
        float* mb1s = (float*)shm;
        float* red = (float*)(shm + 1024);
        mb1s[t] = mb1[t];
        __syncthreads();
        int o0 = (B - 5056) * 8;
        for (int i = 0; i < 8; ++i) {
            int o = o0 + i;
            float part = w3[(size_t)o * 512 + t] * mb1s[t];
            #pragma unroll
            for (int off = 32; off > 0; off >>= 1) part += __shfl_down(part, off);
            if (lane == 0) red[w] = part;
            __syncthreads();
            if (t == 0) bc3[o] = b3[o] + red[0] + red[1] + red[2] + red[3];
            __syncthreads();
        }
        return;
    }

    if (B < 5122) {
        int c = (B - 5120) * 256 + t;
        float acc = 0.f;
        for (int o = 0; o < 512; ++o) acc += sw2[o] * w4[o * 512 + c];
        u[c] = acc;
        return;
    }

    if (t < 128) {
        float s = g1[t] * rsqrtf(v1[t] + EPSV);
        sc1[t] = s; sh1[t] = be1[t] - m1[t] * s;
    }
    {
        float s = g2[t] * rsqrtf(v2[t] + EPSV);
        sc2[t] = s; sh2[t] = be2[t] - m2[t] * s;
        s = g2[t + 256] * rsqrtf(v2[t + 256] + EPSV);
        sc2[t + 256] = s; sh2[t + 256] = be2[t + 256] - m2[t + 256] * s;
    }
    if (t < 64) {
        float part = 0.f;
        #pragma unroll
        for (int i = 0; i < 8; ++i) part += sw2[t * 8 + i] * b4[t * 8 + i];
        #pragma unroll
        for (int off = 32; off > 0; off >>= 1) part += __shfl_down(part, off);
        if (t == 0) ub[0] = sb2[0] + part;
    }
}

// ---------------- fused per-group MLP (4 groups/block, 512 threads) ----------
__global__ __launch_bounds__(512) void mlp_kernel(
    const float* __restrict__ xyz, const int* __restrict__ cidx,
    const int* __restrict__ knn_idx,
    const float* __restrict__ w1, const float* __restrict__ b1,
    const float* __restrict__ sc1, const float* __restrict__ sh1,
    const short* __restrict__ w2fh,
    const float* __restrict__ b2,
    const float* __restrict__ sw1, const float* __restrict__ sb1,
    const short* __restrict__ Pfh, const short* __restrict__ Pfl,
    const float* __restrict__ bc3,
    const short* __restrict__ w3fh,
    const float* __restrict__ sc2, const float* __restrict__ sh2,
    const float* __restrict__ u, const float* __restrict__ ubp,
    short* __restrict__ yh)
{
    __shared__ __align__(16) char smem[78912];
    short* x1 = (short*)smem;                   // [128][128] bf16 swizzled
    short* x2 = (short*)smem;                   // [128][256] bf16 swizzled (overlays x1)
    short* poolA  = (short*)(smem + 65536);     // [8][256] bf16 swizzled (4KB)
    float* fgpart = (float*)(smem + 69632);     // [4][512] f32 (8KB)
    float* feat   = (float*)(smem + 65536);     // [128][13] f32 (6656B, overlays poolA/fgpart; dead after P2)
    float* cen  = (float*)(smem + 77824);       // [4][3]
    float* scs  = (float*)(smem + 77888);       // [128]
    float* sms  = (float*)(smem + 78400);       // [128]

    int gb = blockIdx.x * 4;
    int bq = gb >> 9;
    int t = threadIdx.x;
    int lane = t & 63, wv = t >> 6, q = lane >> 4, r = lane & 15;
    const float* xb = xyz + (size_t)bq * 8192 * 3;

    // P0: centers + scs init
    if (t < 4) {
        int ci = cidx[gb + t];
        cen[t * 3 + 0] = xb[ci * 3 + 0];
        cen[t * 3 + 1] = xb[ci * 3 + 1];
        cen[t * 3 + 2] = xb[ci * 3 + 2];
    }
    if (t < 128) scs[t] = sb1[0];
    __syncthreads();

    // P1: feat gather
    if (t < 128) {
        int gg = t >> 5, kk = t & 31;
        int n = knn_idx[(gb + gg) * 32 + kk];
        float cxx = cen[gg * 3 + 0], cyy = cen[gg * 3 + 1], czz = cen[gg * 3 + 2];
        float nx = xb[n * 3 + 0], ny = xb[n * 3 + 1], nz = xb[n * 3 + 2];
        float rx = cxx - nx, ry = cyy - ny, rz = czz - nz;
        float rd = sqrtf(rx * rx + ry * ry + rz * rz);
        float* fr = feat + t * 13;
        fr[0] = rd; fr[1] = rx; fr[2] = ry; fr[3] = rz;
        fr[4] = cxx; fr[5] = cyy; fr[6] = czz;
        fr[7] = nx; fr[8] = ny; fr[9] = nz;
    }
    __syncthreads();

    // P2: conv1 + BN + ReLU -> x1 bf16 (swizzled)
    for (int i = 0; i < 32; ++i) {
        int flat = t + (i << 9);
        int row = flat >> 7, o = flat & 127;
        const float* wr = w1 + o * 10;
        const float* fr = feat + row * 13;
        float acc = b1[o];
        #pragma unroll
        for (int c = 0; c < 10; ++c) acc += fr[c] * wr[c];
        acc = fmaxf(acc * sc1[o] + sh1[o], 0.f);
        x1[row * 128 + (o ^ ((row & 7) << 3))] = f2bf(acc);
    }
    __syncthreads();

    // P3: conv2 via MFMA (hi-only weights): M=128, N=256, K=128
    f32x4 acc2[8][2];
    #pragma unroll
    for (int rt = 0; rt < 8; ++rt)
        #pragma unroll
        for (int ctl = 0; ctl < 2; ++ctl) {
            float bv = b2[(wv * 2 + ctl) * 16 + r];
            acc2[rt][ctl] = (f32x4){bv, bv, bv, bv};
        }
    #pragma unroll
    for (int ks = 0; ks < 4; ++ks) {
        bf16x8 af[8];
        #pragma unroll
        for (int rt = 0; rt < 8; ++rt) {
            int row = rt * 16 + r;
            int kk = ks * 32 + q * 8;
            af[rt] = *(const bf16x8*)(x1 + row * 128 + (kk ^ ((row & 7) << 3)));
        }
        #pragma unroll
        for (int ctl = 0; ctl < 2; ++ctl) {
            int ct = wv * 2 + ctl;
            size_t woff = ((size_t)(ct * 4 + ks) * 64 + lane) * 8;
            bf16x8 bh = *(const bf16x8*)(w2fh + woff);
            #pragma unroll
            for (int rt = 0; rt < 8; ++rt)
                acc2[rt][ctl] = MFMA16(af[rt], bh, acc2[rt][ctl]);
        }
    }
    // attn1 score partials
    {
        float sw1v[2];
        #pragma unroll
        for (int ctl = 0; ctl < 2; ++ctl) sw1v[ctl] = sw1[(wv * 2 + ctl) * 16 + r];
        #pragma unroll
        for (int rt = 0; rt < 8; ++rt)
            #pragma unroll
            for (int j = 0; j < 4; ++j) {
                float s = sw1v[0] * acc2[rt][0][j] + sw1v[1] * acc2[rt][1][j];
                s += __shfl_xor(s, 1); s += __shfl_xor(s, 2);
                s += __shfl_xor(s, 4); s += __shfl_xor(s, 8);
                if (r == 0) atomicAdd(&scs[rt * 16 + q * 4 + j], s);
            }
    }
    __syncthreads();

    // P4: wave-parallel softmax1 + x2 store
    if (wv < 4 && lane < 32) {
        float s = scs[wv * 32 + lane];
        float mx = s;
        mx = fmaxf(mx, __shfl_xor(mx, 16));
        mx = fmaxf(mx, __shfl_xor(mx, 8));
        mx = fmaxf(mx, __shfl_xor(mx, 4));
        mx = fmaxf(mx, __shfl_xor(mx, 2));
        mx = fmaxf(mx, __shfl_xor(mx, 1));
        float e = expf(s - mx);
        float sum = e;
        sum += __shfl_xor(sum, 16);
        sum += __shfl_xor(sum, 8);
        sum += __shfl_xor(sum, 4);
        sum += __shfl_xor(sum, 2);
        sum += __shfl_xor(sum, 1);
        sms[wv * 32 + lane] = e / sum;
    }
    #pragma unroll
    for (int rt = 0; rt < 8; ++rt)
        #pragma unroll
        for (int ctl = 0; ctl < 2; ++ctl) {
            int ch = (wv * 2 + ctl) * 16 + r;
            #pragma unroll
            for (int j = 0; j < 4; ++j) {
                int row = rt * 16 + q * 4 + j;
                x2[row * 256 + (ch ^ ((row & 7) << 3))] = f2bf(acc2[rt][ctl][j]);
            }
        }
    __syncthreads();

    // P5: pool1 -> poolA bf16 rows (hi: gg, lo: gg+4); scs re-init for attn2
    {
        #pragma unroll
        for (int ctl = 0; ctl < 2; ++ctl)
            #pragma unroll
            for (int gg = 0; gg < 4; ++gg) {
                float p = 0.f;
                #pragma unroll
                for (int rr = 0; rr < 2; ++rr) {
                    int rt = gg * 2 + rr;
                    #pragma unroll
                    for (int j = 0; j < 4; ++j)
                        p += sms[rt * 16 + q * 4 + j] * acc2[rt][ctl][j];
                }
                p += __shfl_xor(p, 16);
                p += __shfl_xor(p, 32);
                if (q == 0) {
                    int ch = (wv * 2 + ctl) * 16 + r;
                    short h, l; bsplit(p, h, l);
                    poolA[gg * 256 + (ch ^ (gg << 3))] = h;
                    poolA[(gg + 4) * 256 + (ch ^ ((gg + 4) << 3))] = l;
                }
            }
        if (t < 128) scs[t] = ubp[0];
    }
    __syncthreads();

    // P6: fgpart via MFMA; A rows 0-7 = poolA, rows 8-15 zero (in regs)
    {
        f32x4 accP[4];
        #pragma unroll
        for (int ctl = 0; ctl < 4; ++ctl) {
            float init = (q == 0) ? bc3[(wv * 4 + ctl) * 16 + r] : 0.f;
            accP[ctl] = (f32x4){init, init, init, init};
        }
        #pragma unroll
        for (int ks = 0; ks < 8; ++ks) {
            int kk = ks * 32 + q * 8;
            bf16x8 pa;
            if (r < 8) pa = *(const bf16x8*)(poolA + r * 256 + (kk ^ (r << 3)));
            else pa = (bf16x8){0, 0, 0, 0, 0, 0, 0, 0};
            #pragma unroll
            for (int ctl = 0; ctl < 4; ++ctl) {
                size_t woff = ((size_t)((wv * 4 + ctl) * 8 + ks) * 64 + lane) * 8;
                bf16x8 ph = *(const bf16x8*)(Pfh + woff);
                bf16x8 pl = *(const bf16x8*)(Pfl + woff);
                accP[ctl] = MFMA16(pa, pl, accP[ctl]);
                accP[ctl] = MFMA16(pa, ph, accP[ctl]);
            }
        }
        #pragma unroll
        for (int ctl = 0; ctl < 4; ++ctl)
            #pragma unroll
            for (int j = 0; j < 4; ++j) {
                float vsum = accP[ctl][j] + __shfl_xor(accP[ctl][j], 16);
                if (q == 0) fgpart[j * 512 + (wv * 4 + ctl) * 16 + r] = vsum;
            }
    }
    __syncthreads();

    // P7: conv3 via MFMA (hi-only weights): M=128, N=512, K=256; C-init = fgpart
    f32x4 acc3[8][4];
    #pragma unroll
    for (int rt = 0; rt < 8; ++rt) {
        int gg = rt >> 1;
        #pragma unroll
        for (int ctl = 0; ctl < 4; ++ctl) {
            float fp = fgpart[gg * 512 + (wv * 4 + ctl) * 16 + r];
            acc3[rt][ctl] = (f32x4){fp, fp, fp, fp};
        }
    }
    #pragma unroll
    for (int ks = 0; ks < 8; ++ks) {
        bf16x8 af[8];
        #pragma unroll
        for (int rt = 0; rt < 8; ++rt) {
            int row = rt * 16 + r;
            int kk = ks * 32 + q * 8;
            af[rt] = *(const bf16x8*)(x2 + row * 256 + (kk ^ ((row & 7) << 3)));
        }
        #pragma unroll
        for (int ctl = 0; ctl < 4; ++ctl) {
            int ct = wv * 4 + ctl;
            size_t woff = ((size_t)(ct * 8 + ks) * 64 + lane) * 8;
            bf16x8 bh = *(const bf16x8*)(w3fh + woff);
            #pragma unroll
            for (int rt = 0; rt < 8; ++rt)
                acc3[rt][ctl] = MFMA16(af[rt], bh, acc3[rt][ctl]);
        }
    }
    // BN2 + ReLU; attn2 score partials
    float uv[4];
    {
        #pragma unroll
        for (int ctl = 0; ctl < 4; ++ctl) {
            int ch = (wv * 4 + ctl) * 16 + r;
            float s = sc2[ch], sh = sh2[ch];
            uv[ctl] = u[ch];
            #pragma unroll
            for (int rt = 0; rt < 8; ++rt)
                #pragma unroll
                for (int j = 0; j < 4; ++j)
                    acc3[rt][ctl][j] = fmaxf(acc3[rt][ctl][j] * s + sh, 0.f);
        }
        #pragma unroll
        for (int rt = 0; rt < 8; ++rt)
            #pragma unroll
            for (int j = 0; j < 4; ++j) {
                float s = uv[0] * acc3[rt][0][j] + uv[1] * acc3[rt][1][j]
                        + uv[2] * acc3[rt][2][j] + uv[3] * acc3[rt][3][j];
                s += __shfl_xor(s, 1); s += __shfl_xor(s, 2);
                s += __shfl_xor(s, 4); s += __shfl_xor(s, 8);
                if (r == 0) atomicAdd(&scs[rt * 16 + q * 4 + j], s);
            }
    }
    __syncthreads();

    // P8: wave-parallel softmax2
    if (wv < 4 && lane < 32) {
        float s = scs[wv * 32 + lane];
        float mx = s;
        mx = fmaxf(mx, __shfl_xor(mx, 16));
        mx = fmaxf(mx, __shfl_xor(mx, 8));
        mx = fmaxf(mx, __shfl_xor(mx, 4));
        mx = fmaxf(mx, __shfl_xor(mx, 2));
        mx = fmaxf(mx, __shfl_xor(mx, 1));
        float e = expf(s - mx);
        float sum = e;
        sum += __shfl_xor(sum, 16);
        sum += __shfl_xor(sum, 8);
        sum += __shfl_xor(sum, 4);
        sum += __shfl_xor(sum, 2);
        sum += __shfl_xor(sum, 1);
        sms[wv * 32 + lane] = e / sum;
    }
    __syncthreads();

    // P9: y[g][ch] = sum_k s[k]*x4[k][ch] -> global bf16
    {
        #pragma unroll
        for (int ctl = 0; ctl < 4; ++ctl)
            #pragma unroll
            for (int gg = 0; gg < 4; ++gg) {
                float p = 0.f;
                #pragma unroll
                for (int rr = 0; rr < 2; ++rr) {
                    int rt = gg * 2 + rr;
                    #pragma unroll
                    for (int j = 0; j < 4; ++j)
                        p += sms[rt * 16 + q * 4 + j] * acc3[rt][ctl][j];
                }
                p += __shfl_xor(p, 16);
                p += __shfl_xor(p, 32);
                if (q == 0) {
                    int grow = gb + gg;
                    int ch = (wv * 4 + ctl) * 16 + r;
                    yh[(size_t)grow * 512 + ch] = f2bf(p);
                }
            }
    }
}

// ---------------- fg2 GEMM: out = bb + y @ MT (M=4096,N=512,K=512) -----------
__global__ __launch_bounds__(256) void fg2_kernel(
    const short* __restrict__ yh,
    const short* __restrict__ MTfh, const short* __restrict__ MTfl,
    const float* __restrict__ bb, float* __restrict__ out_fg2)
{
    int gbase = blockIdx.x * 16;
    int t = threadIdx.x;
    int lane = t & 63, wv = t >> 6, q = lane >> 4, r = lane & 15;
    f32x4 acc[8];
    #pragma unroll
    for (int ctl = 0; ctl < 8; ++ctl) {
        float bv = bb[(wv * 8 + ctl) * 16 + r];
        acc[ctl] = (f32x4){bv, bv, bv, bv};
    }
    #pragma unroll
    for (int ks = 0; ks < 16; ++ks) {
        bf16x8 af = *(const bf16x8*)(yh + (size_t)(gbase + r) * 512 + ks * 32 + q * 8);
        #pragma unroll
        for (int ctl = 0; ctl < 8; ++ctl) {
            int ct = wv * 8 + ctl;
            size_t woff = ((size_t)(ct * 16 + ks) * 64 + lane) * 8;
            bf16x8 bh = *(const bf16x8*)(MTfh + woff);
            bf16x8 bl = *(const bf16x8*)(MTfl + woff);
            acc[ctl] = MFMA16(af, bl, acc[ctl]);
            acc[ctl] = MFMA16(af, bh, acc[ctl]);
        }
    }
    #pragma unroll
    for (int ctl = 0; ctl < 8; ++ctl) {
        int ch = (wv * 8 + ctl) * 16 + r;
        #pragma unroll
        for (int j = 0; j < 4; ++j) {
            int grow = gbase + q * 4 + j;
            out_fg2[(size_t)grow * 512 + ch] = acc[ctl][j];
        }
    }
}

extern "C" void kernel_launch(void* const* d_in, const int* in_sizes, int n_in,
                              void* d_out, int out_size, void* d_ws, size_t ws_size,
                              hipStream_t stream) {
    const float* xyz  = (const float*)d_in[0];
    const int*   cidx = (const int*)d_in[1];
    const float* w1   = (const float*)d_in[2];
    const float* b1   = (const float*)d_in[3];
    const float* g1   = (const float*)d_in[4];
    const float* be1  = (const float*)d_in[5];
    const float* m1   = (const float*)d_in[6];
    const float* v1   = (const float*)d_in[7];
    const float* w2   = (const float*)d_in[8];
    const float* b2   = (const float*)d_in[9];
    const float* sw1  = (const float*)d_in[10];
    const float* sb1  = (const float*)d_in[11];
    const float* mw1  = (const float*)d_in[12];
    const float* mb1  = (const float*)d_in[13];
    const float* w3   = (const float*)d_in[14];
    const float* b3   = (const float*)d_in[15];
    const float* g2   = (const float*)d_in[16];
    const float* be2  = (const float*)d_in[17];
    const float* m2   = (const float*)d_in[18];
    const float* v2   = (const float*)d_in[19];
    const float* w4   = (const float*)d_in[20];
    const float* b4   = (const float*)d_in[21];
    const float* sw2  = (const float*)d_in[22];
    const float* sb2  = (const float*)d_in[23];
    const float* mw2  = (const float*)d_in[24];
    const float* mb2  = (const float*)d_in[25];

    float* out = (float*)d_out;
    char* ws = (char*)d_ws;
    int*   knn_idx = (int*)(ws + 0);             // 524288
    short* w2fh = (short*)(ws + 524288);         // 65536
    short* w3fh = (short*)(ws + 655360);         // 262144
    short* Pfh  = (short*)(ws + 1179648);        // 262144
    short* Pfl  = (short*)(ws + 1441792);        // 262144
    float* bc3  = (float*)(ws + 1703936);        // 2048
    float* sc1  = (float*)(ws + 1705984);        // 512
    float* sh1  = (float*)(ws + 1706496);        // 512
    float* sc2  = (float*)(ws + 1707008);        // 2048
    float* sh2  = (float*)(ws + 1709056);        // 2048
    float* u    = (float*)(ws + 1711104);        // 2048
    float* bb   = (float*)(ws + 1713152);        // 2048
    float* ub   = (float*)(ws + 1715200);        // 256 (pad)
    short* MTfh = (short*)(ws + 1715456);        // 524288
    short* MTfl = (short*)(ws + 2239744);        // 524288
    short* yh   = (short*)(ws + 2764032);        // 4194304

    prep_knn<<<5123, 256, 0, stream>>>(xyz, cidx, knn_idx, out,
                                       w2, w3, mw1, mw2, w4, b4, sw2, sb2, mb2, mb1, b3,
                                       g1, be1, m1, v1, g2, be2, m2, v2,
                                       w2fh, w3fh, Pfh, Pfl, MTfh, MTfl,
                                       sc1, sh1, sc2, sh2, u, bb, ub, bc3);
    mlp_kernel<<<1024, 512, 0, stream>>>(xyz, cidx, knn_idx,
                                         w1, b1, sc1, sh1, w2fh, b2,
                                         sw1, sb1, Pfh, Pfl, bc3, w3fh,
                                         sc2, sh2, u, ub, yh);
    fg2_kernel<<<256, 256, 0, stream>>>(yh, MTfh, MTfl, bb, out + 12288);
}

// Round 7
// 336.607 us; speedup vs baseline: 4.8557x; 1.0854x over previous
//
#include <hip/hip_runtime.h>
#include <math.h>

#define EPSV 1e-5f

typedef __attribute__((ext_vector_type(8))) short bf16x8;
typedef __attribute__((ext_vector_type(4))) float f32x4;

#define MFMA16(a, b, c) __builtin_amdgcn_mfma_f32_16x16x32_bf16(a, b, c, 0, 0, 0)

__device__ __forceinline__ short f2bf(float x) {
    unsigned u = __float_as_uint(x);
    unsigned r = (u + 0x7fffu + ((u >> 16) & 1u)) >> 16;
    return (short)r;
}
__device__ __forceinline__ float bf2f(short h) {
    return __uint_as_float(((unsigned)(unsigned short)h) << 16);
}
__device__ __forceinline__ void bsplit(float x, short& h, short& l) {
    h = f2bf(x);
    l = f2bf(x - bf2f(h));
}

// ============ fused prep + KNN: one launch, roles by blockIdx ================
#define KCAP 2048
__global__ __launch_bounds__(256) void prep_knn(
    const float* __restrict__ xyz, const int* __restrict__ cidx,
    int* __restrict__ knn_idx, float* __restrict__ out_center,
    const float* __restrict__ w1, const float* __restrict__ b1,
    const float* __restrict__ w2, const float* __restrict__ w3,
    const float* __restrict__ mw1, const float* __restrict__ mw2,
    const float* __restrict__ w4, const float* __restrict__ b4,
    const float* __restrict__ sw2, const float* __restrict__ sb2,
    const float* __restrict__ mb2, const float* __restrict__ mb1,
    const float* __restrict__ b3,
    const float* __restrict__ g1, const float* __restrict__ be1,
    const float* __restrict__ m1, const float* __restrict__ v1,
    const float* __restrict__ g2, const float* __restrict__ be2,
    const float* __restrict__ m2, const float* __restrict__ v2,
    short* __restrict__ w1fh, short* __restrict__ w2fh, short* __restrict__ w3fh,
    short* __restrict__ Pfh, short* __restrict__ MTfh,
    float* __restrict__ sc1, float* __restrict__ shb1,
    float* __restrict__ sc2, float* __restrict__ sh2,
    float* __restrict__ u, float* __restrict__ bb, float* __restrict__ ub,
    float* __restrict__ bc3)
{
    __shared__ __align__(16) char shm[12416];
    int B = blockIdx.x, t = threadIdx.x;
    int lane = t & 63, w = t >> 6;

    if (B < 4096) {
        // ---------------- KNN ----------------
        unsigned* cu = (unsigned*)shm;
        unsigned short* cix = (unsigned short*)(shm + 8192);
        unsigned* Tws = (unsigned*)(shm + 12288);
        unsigned* cntS = (unsigned*)(shm + 12304);
        int g = B, b = g >> 9;
        const float* xb = xyz + (size_t)b * 8192 * 3;
        int ci = cidx[g];
        float cx = xb[ci * 3 + 0], cy = xb[ci * 3 + 1], cz = xb[ci * 3 + 2];
        float c2 = cx * cx + cy * cy + cz * cz;
        if (t < 3) out_center[g * 3 + t] = xb[ci * 3 + t];
        if (t == 0) *cntS = 0;

        const float4* p4 = (const float4*)xb + (size_t)t * 24;
        unsigned ue[32];
        unsigned vmin = 0xffffffffu;
        #pragma unroll
        for (int ii = 0; ii < 8; ++ii) {
            float4 v0 = p4[ii * 3 + 0];
            float4 v1 = p4[ii * 3 + 1];
            float4 v2 = p4[ii * 3 + 2];
            float px[4], py[4], pz[4];
            px[0] = v0.x; py[0] = v0.y; pz[0] = v0.z;
            px[1] = v0.w; py[1] = v1.x; pz[1] = v1.y;
            px[2] = v1.z; py[2] = v1.w; pz[2] = v2.x;
            px[3] = v2.y; py[3] = v2.z; pz[3] = v2.w;
            #pragma unroll
            for (int m = 0; m < 4; ++m) {
                float dx = px[m], dy = py[m], dz = pz[m];
                float n2 = dx * dx + dy * dy + dz * dz;
                float d = c2 + n2 - 2.f * (cx * dx + cy * dy + cz * dz);
                unsigned uu = __float_as_uint(d);
                uu = (uu & 0x80000000u) ? ~uu : (uu | 0x80000000u);
                ue[ii * 4 + m] = uu;
                vmin = min(vmin, uu);
            }
        }
        unsigned v = vmin;
        #pragma unroll
        for (int k = 2; k <= 64; k <<= 1) {
            #pragma unroll
            for (int jj = k >> 1; jj > 0; jj >>= 1) {
                unsigned o = __shfl_xor(v, jj);
                bool dir_asc = ((lane & k) == 0) || (k == 64);
                bool lower = (lane & jj) == 0;
                bool take_min = (lower == dir_asc);
                unsigned mn = min(v, o), mx = max(v, o);
                v = take_min ? mn : mx;
            }
        }
        unsigned Tw = __shfl(v, 31);
        if (lane == 0) Tws[w] = Tw;
        __syncthreads();
        unsigned T = min(min(Tws[0], Tws[1]), min(Tws[2], Tws[3]));
        #pragma unroll
        for (int i = 0; i < 32; ++i) {
            if (ue[i] <= T) {
                unsigned pos = atomicAdd(cntS, 1u);
                if (pos < KCAP) {
                    cu[pos] = ue[i];
                    cix[pos] = (unsigned short)(t * 32 + i);
                }
            }
        }
        __syncthreads();
        int C = (int)min(*cntS, (unsigned)KCAP);
        for (int cc = t; cc < C; cc += 256) {
            unsigned uc = cu[cc];
            unsigned short icd = cix[cc];
            int rank = 0;
            for (int j = 0; j < C; ++j) {
                unsigned uj = cu[j];
                rank += (uj < uc) || (uj == uc && cix[j] < icd);
            }
            if (rank < 32) knn_idx[g * 32 + rank] = (int)icd;
        }
        return;
    }

    if (B < 4352) {
        // prep_P: P[c][o] = sum_d mw1[d][c]*w3[o][d]  (hi only)
        float* col = (float*)shm;
        int c = B - 4096;
        col[t] = mw1[t * 256 + c];
        __syncthreads();
        int ks = c >> 5, qq = (c >> 3) & 3, jj = c & 7;
        for (int oo = t; oo < 512; oo += 256) {
            float acc = 0.f;
            for (int d = 0; d < 256; ++d) acc += col[d] * w3[oo * 512 + d];
            int ct = oo >> 4;
            size_t idx = ((size_t)(ct * 8 + ks) * 64 + qq * 16 + (oo & 15)) * 8 + jj;
            Pfh[idx] = f2bf(acc);
        }
        return;
    }

    if (B < 4864) {
        // prep_MT + pack (hi only)
        float* row = (float*)shm;
        int qq = B - 4352;
        row[t] = mw2[(size_t)qq * 512 + t];
        row[t + 256] = mw2[(size_t)qq * 512 + t + 256];
        __syncthreads();
        float a0 = 0.f, a1 = 0.f;
        for (int o = 0; o < 512; ++o) {
            float m = row[o];
            a0 += m * w4[o * 512 + t];
            a1 += m * w4[o * 512 + t + 256];
        }
        int ct = qq >> 4, nl = qq & 15;
        {
            int k = t;
            size_t i0 = (((size_t)(ct * 16 + (k >> 5))) << 9)
                      | ((((k >> 3) & 3) * 16 + nl) << 3) | (k & 7);
            MTfh[i0] = f2bf(a0);
        }
        {
            int k = t + 256;
            size_t i1 = (((size_t)(ct * 16 + (k >> 5))) << 9)
                      | ((((k >> 3) & 3) * 16 + nl) << 3) | (k & 7);
            MTfh[i1] = f2bf(a1);
        }
        return;
    }

    if (B < 4992) {
        // w2/w3 fragment packing (hi only)
        int tid = (B - 4864) * 256 + t;
        {
            int i = tid;
            int j = i & 7, ln = (i >> 3) & 63, rest = i >> 9;
            int ks = rest & 3, ct = rest >> 2;
            int o = ct * 16 + (ln & 15);
            int k = ks * 32 + (ln >> 4) * 8 + j;
            w2fh[i] = f2bf(w2[o * 128 + k]);
        }
        #pragma unroll
        for (int s = 0; s < 4; ++s) {
            int i = tid + s * 32768;
            int j = i & 7, ln = (i >> 3) & 63, rest = i >> 9;
            int ks = rest & 7, ct = rest >> 3;
            int o = ct * 16 + (ln & 15);
            int c = 256 + ks * 32 + (ln >> 4) * 8 + j;
            w3fh[i] = f2bf(w3[o * 512 + c]);
        }
        return;
    }

    if (B < 5056) {
        float* b4s = (float*)shm;
        float* red = (float*)(shm + 2048);
        b4s[t] = b4[t];
        b4s[t + 256] = b4[t + 256];
        __syncthreads();
        int q0 = (B - 4992) * 8;
        for (int i = 0; i < 8; ++i) {
            int q = q0 + i;
            float part = mw2[(size_t)q * 512 + t] * b4s[t]
                       + mw2[(size_t)q * 512 + 256 + t] * b4s[256 + t];
            #pragma unroll
            for (int off = 32; off > 0; off >>= 1) part += __shfl_down(part, off);
            if (lane == 0) red[w] = part;
            __syncthreads();
            if (t == 0) bb[q] = mb2[q] + red[0] + red[1] + red[2] + red[3];
            __syncthreads();
        }
        return;
    }

    if (B < 5120) {
        float* mb1s = (float*)shm;
        float* red = (float*)(shm + 1024);
        mb1s[t] = mb1[t];
        __syncthreads();
        int o0 = (B - 5056) * 8;
        for (int i = 0; i < 8; ++i) {
            int o = o0 + i;
            float part = w3[(size_t)o * 512 + t] * mb1s[t];
            #pragma unroll
            for (int off = 32; off > 0; off >>= 1) part += __shfl_down(part, off);
            if (lane == 0) red[w] = part;
            __syncthreads();
            if (t == 0) bc3[o] = b3[o] + red[0] + red[1] + red[2] + red[3];
            __syncthreads();
        }
        return;
    }

    if (B < 5122) {
        int c = (B - 5120) * 256 + t;
        float acc = 0.f;
        for (int o = 0; o < 512; ++o) acc += sw2[o] * w4[o * 512 + c];
        u[c] = acc;
        return;
    }

    // ---- scales + shb1 + w1 frags + ub ----
    if (t < 128) {
        float s = g1[t] * rsqrtf(v1[t] + EPSV);
        float sh = be1[t] - m1[t] * s;
        sc1[t] = s;
        shb1[t] = b1[t] * s + sh;
    }
    {
        float s = g2[t] * rsqrtf(v2[t] + EPSV);
        sc2[t] = s; sh2[t] = be2[t] - m2[t] * s;
        s = g2[t + 256] * rsqrtf(v2[t + 256] + EPSV);
        sc2[t + 256] = s; sh2[t + 256] = be2[t + 256] - m2[t + 256] * s;
    }
    #pragma unroll
    for (int s = 0; s < 16; ++s) {
        int i = t + s * 256;                 // 0..4095
        int j = i & 7, ln = (i >> 3) & 63, ct = i >> 9;
        int o = ct * 16 + (ln & 15);
        int k = (ln >> 4) * 8 + j;
        w1fh[i] = (k < 10) ? f2bf(w1[o * 10 + k]) : (short)0;
    }
    if (t < 64) {
        float part = 0.f;
        #pragma unroll
        for (int i = 0; i < 8; ++i) part += sw2[t * 8 + i] * b4[t * 8 + i];
        #pragma unroll
        for (int off = 32; off > 0; off >>= 1) part += __shfl_down(part, off);
        if (t == 0) ub[0] = sb2[0] + part;
    }
}

// ---------------- fused per-group MLP (4 groups/block, 512 threads) ----------
__global__ __launch_bounds__(512) void mlp_kernel(
    const float* __restrict__ xyz, const int* __restrict__ cidx,
    const int* __restrict__ knn_idx,
    const short* __restrict__ w1fh,
    const float* __restrict__ sc1, const float* __restrict__ shb1,
    const short* __restrict__ w2fh,
    const float* __restrict__ b2,
    const float* __restrict__ sw1, const float* __restrict__ sb1,
    const short* __restrict__ Pfh, const float* __restrict__ bc3,
    const short* __restrict__ w3fh,
    const float* __restrict__ sc2, const float* __restrict__ sh2,
    const float* __restrict__ u, const float* __restrict__ ubp,
    short* __restrict__ yh)
{
    __shared__ __align__(16) char smem[70784];
    short* x1 = (short*)smem;                   // [128][128] bf16 swizzled
    short* x2 = (short*)smem;                   // [128][256] bf16 swizzled (overlays x1)
    short* feat_h = (short*)(smem + 32768);     // [128][32] bf16 (8KB, inside x2 hi half, dead after P2)
    short* feat_l = (short*)(smem + 40960);     // [128][32] bf16 (8KB)
    short* poolA  = (short*)(smem + 65536);     // [8][256] bf16 swizzled (4KB)
    float* cen  = (float*)(smem + 69632);       // [4][3]
    float* scs  = (float*)(smem + 69696);       // [128]
    float* sms  = (float*)(smem + 70208);       // [128]

    int gb = blockIdx.x * 4;
    int bq = gb >> 9;
    int t = threadIdx.x;
    int lane = t & 63, wv = t >> 6, q = lane >> 4, r = lane & 15;
    const float* xb = xyz + (size_t)bq * 8192 * 3;

    // P0: centers + scs init
    if (t < 4) {
        int ci = cidx[gb + t];
        cen[t * 3 + 0] = xb[ci * 3 + 0];
        cen[t * 3 + 1] = xb[ci * 3 + 1];
        cen[t * 3 + 2] = xb[ci * 3 + 2];
    }
    if (t < 128) scs[t] = sb1[0];
    __syncthreads();

    // P1: feat gather -> feat_h/feat_l [128][32] bf16, k>=10 zero
    if (t < 128) {
        int gg = t >> 5, kk = t & 31;
        int n = knn_idx[(gb + gg) * 32 + kk];
        float cxx = cen[gg * 3 + 0], cyy = cen[gg * 3 + 1], czz = cen[gg * 3 + 2];
        float nx = xb[n * 3 + 0], ny = xb[n * 3 + 1], nz = xb[n * 3 + 2];
        float rx = cxx - nx, ry = cyy - ny, rz = czz - nz;
        float rd = sqrtf(rx * rx + ry * ry + rz * rz);
        float f[10];
        f[0] = rd; f[1] = rx; f[2] = ry; f[3] = rz;
        f[4] = cxx; f[5] = cyy; f[6] = czz;
        f[7] = nx; f[8] = ny; f[9] = nz;
        short* fh = feat_h + t * 32;
        short* fl = feat_l + t * 32;
        #pragma unroll
        for (int c = 0; c < 10; ++c) {
            short h, l; bsplit(f[c], h, l);
            fh[c] = h; fl[c] = l;
        }
        #pragma unroll
        for (int c = 10; c < 32; ++c) { fh[c] = 0; fl[c] = 0; }
    }
    __syncthreads();

    // P2: conv1 via MFMA: M=128, N=128 (wave: 1 ct = wv), K=32 (10 real)
    {
        f32x4 acc1[8];
        #pragma unroll
        for (int rt = 0; rt < 8; ++rt) acc1[rt] = (f32x4){0.f, 0.f, 0.f, 0.f};
        bf16x8 bw = *(const bf16x8*)(w1fh + ((size_t)wv * 64 + lane) * 8);
        #pragma unroll
        for (int rt = 0; rt < 8; ++rt) {
            int row = rt * 16 + r;
            bf16x8 ah = *(const bf16x8*)(feat_h + row * 32 + q * 8);
            bf16x8 al = *(const bf16x8*)(feat_l + row * 32 + q * 8);
            acc1[rt] = MFMA16(al, bw, acc1[rt]);
            acc1[rt] = MFMA16(ah, bw, acc1[rt]);
        }
        int o = wv * 16 + r;
        float s1v = sc1[o], sbv = shb1[o];
        #pragma unroll
        for (int rt = 0; rt < 8; ++rt)
            #pragma unroll
            for (int j = 0; j < 4; ++j) {
                int row = rt * 16 + q * 4 + j;
                float vv = fmaxf(acc1[rt][j] * s1v + sbv, 0.f);
                x1[row * 128 + (o ^ ((row & 7) << 3))] = f2bf(vv);
            }
    }
    __syncthreads();

    // P3: conv2 via MFMA (hi weights): M=128, N=256 (wave: 2 ct), K=128
    f32x4 acc2[8][2];
    #pragma unroll
    for (int rt = 0; rt < 8; ++rt)
        #pragma unroll
        for (int ctl = 0; ctl < 2; ++ctl) {
            float bv = b2[(wv * 2 + ctl) * 16 + r];
            acc2[rt][ctl] = (f32x4){bv, bv, bv, bv};
        }
    #pragma unroll
    for (int ks = 0; ks < 4; ++ks) {
        bf16x8 af[8];
        #pragma unroll
        for (int rt = 0; rt < 8; ++rt) {
            int row = rt * 16 + r;
            int kk = ks * 32 + q * 8;
            af[rt] = *(const bf16x8*)(x1 + row * 128 + (kk ^ ((row & 7) << 3)));
        }
        #pragma unroll
        for (int ctl = 0; ctl < 2; ++ctl) {
            int ct = wv * 2 + ctl;
            size_t woff = ((size_t)(ct * 4 + ks) * 64 + lane) * 8;
            bf16x8 bh = *(const bf16x8*)(w2fh + woff);
            #pragma unroll
            for (int rt = 0; rt < 8; ++rt)
                acc2[rt][ctl] = MFMA16(af[rt], bh, acc2[rt][ctl]);
        }
    }
    // attn1 score partials
    {
        float sw1v[2];
        #pragma unroll
        for (int ctl = 0; ctl < 2; ++ctl) sw1v[ctl] = sw1[(wv * 2 + ctl) * 16 + r];
        #pragma unroll
        for (int rt = 0; rt < 8; ++rt)
            #pragma unroll
            for (int j = 0; j < 4; ++j) {
                float s = sw1v[0] * acc2[rt][0][j] + sw1v[1] * acc2[rt][1][j];
                s += __shfl_xor(s, 1); s += __shfl_xor(s, 2);
                s += __shfl_xor(s, 4); s += __shfl_xor(s, 8);
                if (r == 0) atomicAdd(&scs[rt * 16 + q * 4 + j], s);
            }
    }
    __syncthreads();

    // P4: wave-parallel softmax1 + x2 store
    if (wv < 4 && lane < 32) {
        float s = scs[wv * 32 + lane];
        float mx = s;
        mx = fmaxf(mx, __shfl_xor(mx, 16));
        mx = fmaxf(mx, __shfl_xor(mx, 8));
        mx = fmaxf(mx, __shfl_xor(mx, 4));
        mx = fmaxf(mx, __shfl_xor(mx, 2));
        mx = fmaxf(mx, __shfl_xor(mx, 1));
        float e = expf(s - mx);
        float sum = e;
        sum += __shfl_xor(sum, 16);
        sum += __shfl_xor(sum, 8);
        sum += __shfl_xor(sum, 4);
        sum += __shfl_xor(sum, 2);
        sum += __shfl_xor(sum, 1);
        sms[wv * 32 + lane] = e / sum;
    }
    #pragma unroll
    for (int rt = 0; rt < 8; ++rt)
        #pragma unroll
        for (int ctl = 0; ctl < 2; ++ctl) {
            int ch = (wv * 2 + ctl) * 16 + r;
            #pragma unroll
            for (int j = 0; j < 4; ++j) {
                int row = rt * 16 + q * 4 + j;
                x2[row * 256 + (ch ^ ((row & 7) << 3))] = f2bf(acc2[rt][ctl][j]);
            }
        }
    __syncthreads();

    // P5: pool1 -> poolA bf16 rows (hi: gg, lo: gg+4); scs re-init for attn2
    {
        #pragma unroll
        for (int ctl = 0; ctl < 2; ++ctl)
            #pragma unroll
            for (int gg = 0; gg < 4; ++gg) {
                float p = 0.f;
                #pragma unroll
                for (int rr = 0; rr < 2; ++rr) {
                    int rt = gg * 2 + rr;
                    #pragma unroll
                    for (int j = 0; j < 4; ++j)
                        p += sms[rt * 16 + q * 4 + j] * acc2[rt][ctl][j];
                }
                p += __shfl_xor(p, 16);
                p += __shfl_xor(p, 32);
                if (q == 0) {
                    int ch = (wv * 2 + ctl) * 16 + r;
                    short h, l; bsplit(p, h, l);
                    poolA[gg * 256 + (ch ^ (gg << 3))] = h;
                    poolA[(gg + 4) * 256 + (ch ^ ((gg + 4) << 3))] = l;
                }
            }
        if (t < 128) scs[t] = ubp[0];
    }
    __syncthreads();

    // P6: pool@P via MFMA (registers only; A rows 0-7 = poolA hi/lo, 8-15 zero)
    float fgv[4][4];   // [ctl][group]
    float bc3v[4];
    {
        f32x4 accP[4];
        #pragma unroll
        for (int ctl = 0; ctl < 4; ++ctl) accP[ctl] = (f32x4){0.f, 0.f, 0.f, 0.f};
        #pragma unroll
        for (int ks = 0; ks < 8; ++ks) {
            int kk = ks * 32 + q * 8;
            bf16x8 pa;
            if (r < 8) pa = *(const bf16x8*)(poolA + r * 256 + (kk ^ (r << 3)));
            else pa = (bf16x8){0, 0, 0, 0, 0, 0, 0, 0};
            #pragma unroll
            for (int ctl = 0; ctl < 4; ++ctl) {
                size_t woff = ((size_t)((wv * 4 + ctl) * 8 + ks) * 64 + lane) * 8;
                bf16x8 ph = *(const bf16x8*)(Pfh + woff);
                accP[ctl] = MFMA16(pa, ph, accP[ctl]);
            }
        }
        #pragma unroll
        for (int ctl = 0; ctl < 4; ++ctl) {
            bc3v[ctl] = bc3[(wv * 4 + ctl) * 16 + r];
            #pragma unroll
            for (int j = 0; j < 4; ++j) {
                float x = accP[ctl][j];
                x += __shfl_xor(x, 16);
                x += __shfl_xor(x, 32);
                fgv[ctl][j] = x;
            }
        }
    }

    // P7: conv3 via MFMA (hi weights): M=128, N=512, K=256; init = fgv + bc3
    f32x4 acc3[8][4];
    #pragma unroll
    for (int rt = 0; rt < 8; ++rt) {
        int gg = rt >> 1;
        #pragma unroll
        for (int ctl = 0; ctl < 4; ++ctl) {
            float fp = fgv[ctl][gg] + bc3v[ctl];
            acc3[rt][ctl] = (f32x4){fp, fp, fp, fp};
        }
    }
    #pragma unroll
    for (int ks = 0; ks < 8; ++ks) {
        bf16x8 af[8];
        #pragma unroll
        for (int rt = 0; rt < 8; ++rt) {
            int row = rt * 16 + r;
            int kk = ks * 32 + q * 8;
            af[rt] = *(const bf16x8*)(x2 + row * 256 + (kk ^ ((row & 7) << 3)));
        }
        #pragma unroll
        for (int ctl = 0; ctl < 4; ++ctl) {
            int ct = wv * 4 + ctl;
            size_t woff = ((size_t)(ct * 8 + ks) * 64 + lane) * 8;
            bf16x8 bh = *(const bf16x8*)(w3fh + woff);
            #pragma unroll
            for (int rt = 0; rt < 8; ++rt)
                acc3[rt][ctl] = MFMA16(af[rt], bh, acc3[rt][ctl]);
        }
    }
    // BN2 + ReLU; attn2 score partials
    float uv[4];
    {
        #pragma unroll
        for (int ctl = 0; ctl < 4; ++ctl) {
            int ch = (wv * 4 + ctl) * 16 + r;
            float s = sc2[ch], sh = sh2[ch];
            uv[ctl] = u[ch];
            #pragma unroll
            for (int rt = 0; rt < 8; ++rt)
                #pragma unroll
                for (int j = 0; j < 4; ++j)
                    acc3[rt][ctl][j] = fmaxf(acc3[rt][ctl][j] * s + sh, 0.f);
        }
        #pragma unroll
        for (int rt = 0; rt < 8; ++rt)
            #pragma unroll
            for (int j = 0; j < 4; ++j) {
                float s = uv[0] * acc3[rt][0][j] + uv[1] * acc3[rt][1][j]
                        + uv[2] * acc3[rt][2][j] + uv[3] * acc3[rt][3][j];
                s += __shfl_xor(s, 1); s += __shfl_xor(s, 2);
                s += __shfl_xor(s, 4); s += __shfl_xor(s, 8);
                if (r == 0) atomicAdd(&scs[rt * 16 + q * 4 + j], s);
            }
    }
    __syncthreads();

    // P8: wave-parallel softmax2
    if (wv < 4 && lane < 32) {
        float s = scs[wv * 32 + lane];
        float mx = s;
        mx = fmaxf(mx, __shfl_xor(mx, 16));
        mx = fmaxf(mx, __shfl_xor(mx, 8));
        mx = fmaxf(mx, __shfl_xor(mx, 4));
        mx = fmaxf(mx, __shfl_xor(mx, 2));
        mx = fmaxf(mx, __shfl_xor(mx, 1));
        float e = expf(s - mx);
        float sum = e;
        sum += __shfl_xor(sum, 16);
        sum += __shfl_xor(sum, 8);
        sum += __shfl_xor(sum, 4);
        sum += __shfl_xor(sum, 2);
        sum += __shfl_xor(sum, 1);
        sms[wv * 32 + lane] = e / sum;
    }
    __syncthreads();

    // P9: y[g][ch] = sum_k s[k]*x4[k][ch] -> global bf16
    {
        #pragma unroll
        for (int ctl = 0; ctl < 4; ++ctl)
            #pragma unroll
            for (int gg = 0; gg < 4; ++gg) {
                float p = 0.f;
                #pragma unroll
                for (int rr = 0; rr < 2; ++rr) {
                    int rt = gg * 2 + rr;
                    #pragma unroll
                    for (int j = 0; j < 4; ++j)
                        p += sms[rt * 16 + q * 4 + j] * acc3[rt][ctl][j];
                }
                p += __shfl_xor(p, 16);
                p += __shfl_xor(p, 32);
                if (q == 0) {
                    int grow = gb + gg;
                    int ch = (wv * 4 + ctl) * 16 + r;
                    yh[(size_t)grow * 512 + ch] = f2bf(p);
                }
            }
    }
}

// ---------------- fg2 GEMM: out = bb + y @ MT (hi-only) ----------------------
__global__ __launch_bounds__(256) void fg2_kernel(
    const short* __restrict__ yh,
    const short* __restrict__ MTfh,
    const float* __restrict__ bb, float* __restrict__ out_fg2)
{
    int gbase = blockIdx.x * 16;
    int t = threadIdx.x;
    int lane = t & 63, wv = t >> 6, q = lane >> 4, r = lane & 15;
    f32x4 acc[8];
    #pragma unroll
    for (int ctl = 0; ctl < 8; ++ctl) {
        float bv = bb[(wv * 8 + ctl) * 16 + r];
        acc[ctl] = (f32x4){bv, bv, bv, bv};
    }
    #pragma unroll
    for (int ks = 0; ks < 16; ++ks) {
        bf16x8 af = *(const bf16x8*)(yh + (size_t)(gbase + r) * 512 + ks * 32 + q * 8);
        #pragma unroll
        for (int ctl = 0; ctl < 8; ++ctl) {
            int ct = wv * 8 + ctl;
            size_t woff = ((size_t)(ct * 16 + ks) * 64 + lane) * 8;
            bf16x8 bh = *(const bf16x8*)(MTfh + woff);
            acc[ctl] = MFMA16(af, bh, acc[ctl]);
        }
    }
    #pragma unroll
    for (int ctl = 0; ctl < 8; ++ctl) {
        int ch = (wv * 8 + ctl) * 16 + r;
        #pragma unroll
        for (int j = 0; j < 4; ++j) {
            int grow = gbase + q * 4 + j;
            out_fg2[(size_t)grow * 512 + ch] = acc[ctl][j];
        }
    }
}

extern "C" void kernel_launch(void* const* d_in, const int* in_sizes, int n_in,
                              void* d_out, int out_size, void* d_ws, size_t ws_size,
                              hipStream_t stream) {
    const float* xyz  = (const float*)d_in[0];
    const int*   cidx = (const int*)d_in[1];
    const float* w1   = (const float*)d_in[2];
    const float* b1   = (const float*)d_in[3];
    const float* g1   = (const float*)d_in[4];
    const float* be1  = (const float*)d_in[5];
    const float* m1   = (const float*)d_in[6];
    const float* v1   = (const float*)d_in[7];
    const float* w2   = (const float*)d_in[8];
    const float* b2   = (const float*)d_in[9];
    const float* sw1  = (const float*)d_in[10];
    const float* sb1  = (const float*)d_in[11];
    const float* mw1  = (const float*)d_in[12];
    const float* mb1  = (const float*)d_in[13];
    const float* w3   = (const float*)d_in[14];
    const float* b3   = (const float*)d_in[15];
    const float* g2   = (const float*)d_in[16];
    const float* be2  = (const float*)d_in[17];
    const float* m2   = (const float*)d_in[18];
    const float* v2   = (const float*)d_in[19];
    const float* w4   = (const float*)d_in[20];
    const float* b4   = (const float*)d_in[21];
    const float* sw2  = (const float*)d_in[22];
    const float* sb2  = (const float*)d_in[23];
    const float* mw2  = (const float*)d_in[24];
    const float* mb2  = (const float*)d_in[25];

    float* out = (float*)d_out;
    char* ws = (char*)d_ws;
    int*   knn_idx = (int*)(ws + 0);             // 524288
    short* w2fh = (short*)(ws + 524288);         // 65536
    short* w3fh = (short*)(ws + 655360);         // 262144
    short* Pfh  = (short*)(ws + 1179648);        // 262144
    short* w1fh = (short*)(ws + 1441792);        // 8192
    float* bc3  = (float*)(ws + 1703936);        // 2048
    float* sc1  = (float*)(ws + 1705984);        // 512
    float* shb1 = (float*)(ws + 1706496);        // 512
    float* sc2  = (float*)(ws + 1707008);        // 2048
    float* sh2  = (float*)(ws + 1709056);        // 2048
    float* u    = (float*)(ws + 1711104);        // 2048
    float* bb   = (float*)(ws + 1713152);        // 2048
    float* ub   = (float*)(ws + 1715200);        // 256 (pad)
    short* MTfh = (short*)(ws + 1715456);        // 524288
    short* yh   = (short*)(ws + 2764032);        // 4194304

    prep_knn<<<5123, 256, 0, stream>>>(xyz, cidx, knn_idx, out,
                                       w1, b1, w2, w3, mw1, mw2, w4, b4, sw2, sb2,
                                       mb2, mb1, b3,
                                       g1, be1, m1, v1, g2, be2, m2, v2,
                                       w1fh, w2fh, w3fh, Pfh, MTfh,
                                       sc1, shb1, sc2, sh2, u, bb, ub, bc3);
    mlp_kernel<<<1024, 512, 0, stream>>>(xyz, cidx, knn_idx,
                                         w1fh, sc1, shb1, w2fh, b2,
                                         sw1, sb1, Pfh, bc3, w3fh,
                                         sc2, sh2, u, ub, yh);
    fg2_kernel<<<256, 256, 0, stream>>>(yh, MTfh, bb, out + 12288);
}